// Round 6
// baseline (196.758 us; speedup 1.0000x reference)
//
#include <hip/hip_runtime.h>
#include <math.h>

// Problem constants
#define BB_ 8
#define C_ 512
#define C3_ 1536
#define HW_ 1024
#define NH_ 8
#define DH_ 64
#define HH_ 32
#define WW_ 32

typedef __attribute__((ext_vector_type(8))) short short8;
typedef __attribute__((ext_vector_type(4))) short short4v;
typedef __attribute__((ext_vector_type(8))) unsigned short ushort8;
typedef __attribute__((ext_vector_type(4))) unsigned short ushort4_t;
typedef __attribute__((ext_vector_type(4))) float f32x4;
typedef unsigned short ushort;

__device__ inline ushort f2bf(float f) {
  union { float f; unsigned u; } v;
  v.f = f;
  unsigned r = v.u + 0x7fffu + ((v.u >> 16) & 1u);
  return (ushort)(r >> 16);
}
__device__ inline float bf2f(ushort u) {
  union { unsigned u; float f; } v;
  v.u = ((unsigned)u) << 16;
  return v.f;
}

// One-instruction RNE pack of two f32 -> two bf16 (lo=a, hi=b).
__device__ inline unsigned cvt_pk_bf16(float a, float b) {
  unsigned r;
  asm("v_cvt_pk_bf16_f32 %0, %1, %2" : "=v"(r) : "v"(a), "v"(b));
  return r;
}

__device__ inline float fast_exp2(float x) {
#if __has_builtin(__builtin_amdgcn_exp2f)
  return __builtin_amdgcn_exp2f(x);
#else
  return exp2f(x);
#endif
}

#define GLD16(gptr, lptr)                                                     \
  __builtin_amdgcn_global_load_lds(                                           \
      (const __attribute__((address_space(1))) unsigned int*)(gptr),          \
      (__attribute__((address_space(3))) unsigned int*)(lptr), 16, 0, 0)

// -------------------------------------------------------------------------
// K1 (prep): fused weight-cvt (x4 vectorized) + x transpose(+pos) +
// qsum/ksum zeroing. Grid: 1024 transpose + 1280 wcvt + 32 sums = 2336.
__global__ __launch_bounds__(256) void prep_kernel(
    const float* __restrict__ x, const float* __restrict__ pos,
    const float* __restrict__ qkv_w, const float* __restrict__ proj_w,
    const float* __restrict__ pw_w, ushort* __restrict__ t,
    ushort* __restrict__ xT, ushort* __restrict__ wts,
    float* __restrict__ sums) {
  const int bid = blockIdx.x;
  const int tid = threadIdx.x;
  if (bid >= 2304) {
    sums[(bid - 2304) * 256 + tid] = 0.f;
    return;
  }
  if (bid >= 1024) {
    int i = ((bid - 1024) * 256 + tid) * 4;
    float4 v;
    if (i < 786432) v = *(const float4*)&qkv_w[i];
    else if (i < 1048576) v = *(const float4*)&proj_w[i - 786432];
    else v = *(const float4*)&pw_w[i - 1048576];
    union { unsigned u[2]; ushort4_t s; } o4;
    o4.u[0] = cvt_pk_bf16(v.x, v.y);
    o4.u[1] = cvt_pk_bf16(v.z, v.w);
    *(ushort4_t*)&wts[i] = o4.s;
    return;
  }
  __shared__ float tile[64][65];
  const int n0 = (bid & 15) * 64, c0 = ((bid >> 4) & 7) * 64, b = bid >> 7;
#pragma unroll
  for (int it = 0; it < 4; it++) {
    int c_l = (tid >> 4) + it * 16;
    int n_l4 = (tid & 15) * 4;
    float4 v = *(const float4*)&x[((size_t)(b * C_ + c0 + c_l)) * HW_ + n0 + n_l4];
    tile[c_l][n_l4 + 0] = v.x;
    tile[c_l][n_l4 + 1] = v.y;
    tile[c_l][n_l4 + 2] = v.z;
    tile[c_l][n_l4 + 3] = v.w;
  }
  __syncthreads();
#pragma unroll
  for (int it = 0; it < 4; it++) {
    int n_l = (tid >> 4) + it * 16;
    int c_l4 = (tid & 15) * 4;
    size_t token = (size_t)(b * HW_ + n0 + n_l);
    float4 pv = *(const float4*)&pos[(n0 + n_l) * C_ + c0 + c_l4];
    float xv0 = tile[c_l4 + 0][n_l], xv1 = tile[c_l4 + 1][n_l];
    float xv2 = tile[c_l4 + 2][n_l], xv3 = tile[c_l4 + 3][n_l];
    ushort4_t tb = {f2bf(xv0 + pv.x), f2bf(xv1 + pv.y), f2bf(xv2 + pv.z),
                    f2bf(xv3 + pv.w)};
    ushort4_t xb = {f2bf(xv0), f2bf(xv1), f2bf(xv2), f2bf(xv3)};
    *(ushort4_t*)&t[token * C_ + c0 + c_l4] = tb;
    *(ushort4_t*)&xT[token * C_ + c0 + c_l4] = xb;
  }
}

// -------------------------------------------------------------------------
// K2: qkv GEMM, BK=64 (8 K-steps). Row-swizzled 8-chunk LDS.
// Single-buffered (grid 768 = 3 blocks/CU; dbuf would drop residency).
// Epilogue: q/k bf16 + norm-sums; V -> transposed bf16 into vt.
__global__ __launch_bounds__(256) void gemm_qkv(
    const ushort* __restrict__ A, const ushort* __restrict__ Wm,
    ushort* __restrict__ out, ushort* __restrict__ vt,
    float* __restrict__ qsum, float* __restrict__ ksum) {
  const int N = C3_, K = C_;
  __shared__ alignas(16) ushort As[128 * 64];
  __shared__ alignas(16) ushort Bs[128 * 64];
  const int bn = blockIdx.x * 128, bm = blockIdx.y * 128;
  const int tid = threadIdx.x;
  const int w = tid >> 6, lane = tid & 63;
  const int wm = 64 * (w & 1), wn = 64 * (w >> 1);
  const int l15 = lane & 15, lq = lane >> 4;

  f32x4 acc[4][4];
#pragma unroll
  for (int i = 0; i < 4; i++)
#pragma unroll
    for (int j = 0; j < 4; j++) acc[i][j] = (f32x4){0.f, 0.f, 0.f, 0.f};

  const int srr8 = lane >> 3, sq3 = lane & 7;

  for (int k0 = 0; k0 < K; k0 += 64) {
    __syncthreads();
#pragma unroll
    for (int it = 0; it < 4; it++) {
      int r = w * 32 + it * 8 + srr8;
      int g = (sq3 - r) & 7;
      GLD16(A + (size_t)(bm + r) * K + k0 + g * 8, &As[(w * 32 + it * 8) * 64]);
      GLD16(Wm + (size_t)(bn + r) * K + k0 + g * 8, &Bs[(w * 32 + it * 8) * 64]);
    }
    __syncthreads();
#pragma unroll
    for (int kk = 0; kk < 2; kk++) {
      short8 af[4], bf[4];
#pragma unroll
      for (int nt = 0; nt < 4; nt++) {
        int r = wm + nt * 16 + l15;
        af[nt] = *(const short8*)&As[r * 64 + (((kk * 4 + lq) + r) & 7) * 8];
        int c = wn + nt * 16 + l15;
        bf[nt] = *(const short8*)&Bs[c * 64 + (((kk * 4 + lq) + c) & 7) * 8];
      }
#pragma unroll
      for (int i = 0; i < 4; i++)
#pragma unroll
        for (int j = 0; j < 4; j++)
          acc[i][j] = __builtin_amdgcn_mfma_f32_16x16x32_bf16(
              af[i], bf[j], acc[i][j], 0, 0, 0);
    }
  }

  const int b = bm >> 10;
  if (bn < 1024) {
#pragma unroll
    for (int j = 0; j < 4; j++) {
      int c = bn + wn + j * 16 + l15;
      float ss = 0.f;
#pragma unroll
      for (int i = 0; i < 4; i++) {
#pragma unroll
        for (int r = 0; r < 4; r++) {
          int m = bm + wm + i * 16 + lq * 4 + r;
          float v = acc[i][j][r];
          ss += v * v;
          out[(size_t)m * N + c] = f2bf(v);
        }
      }
      ss += __shfl_xor(ss, 16);
      ss += __shfl_xor(ss, 32);
      if (lq == 0) {
        if (c < 512) atomicAdd(&qsum[b * 512 + c], ss);
        else atomicAdd(&ksum[b * 512 + c - 512], ss);
      }
    }
  } else {
#pragma unroll
    for (int j = 0; j < 4; j++) {
      int c = bn + wn + j * 16 + l15;
      int hd = c - 1024;
      ushort* vrow = vt + ((size_t)(b * 512 + hd)) * HW_;
#pragma unroll
      for (int i = 0; i < 4; i++) {
        int n0 = (bm & 1023) + wm + i * 16 + lq * 4;
        union { unsigned u[2]; ushort4_t s; } pu;
        pu.u[0] = cvt_pk_bf16(acc[i][j][0], acc[i][j][1]);
        pu.u[1] = cvt_pk_bf16(acc[i][j][2], acc[i][j][3]);
        *(ushort4_t*)&vrow[n0] = pu.s;
      }
    }
  }
}

// -------------------------------------------------------------------------
// bf16 MFMA GEMM 128x64 tiles, BK=64 (8 K-steps), DOUBLE-BUFFERED staging:
// per K-step, issue GLDs for step+1 into the other buffer, then MFMA the
// current buffer — loads fly under compute; one barrier per step.
// LDS 80 KB -> still 2 blocks/CU (grid 512 fully resident).
// EPI 2 (pointwise conv): f32 +bias +resid(bf16), NCHW via swizzled Cs.
template <int EPI>
__global__ __launch_bounds__(256) void gemm_n64(
    const ushort* __restrict__ A, const ushort* __restrict__ Wm,
    const float* __restrict__ bias, void* __restrict__ outv,
    const ushort* __restrict__ resid, int N, int K) {
  __shared__ alignas(16) ushort As[2][128 * 64];
  __shared__ alignas(16) ushort Bs[2][64 * 64];
  __shared__ alignas(16) float Cs[EPI == 2 ? 64 * 128 : 4];
  const int bn = blockIdx.x * 64, bm = blockIdx.y * 128;
  const int tid = threadIdx.x;
  const int w = tid >> 6, lane = tid & 63;
  const int wm = 64 * (w & 1), wn = 32 * (w >> 1);
  const int l15 = lane & 15, lq = lane >> 4;

  f32x4 acc[4][2];
#pragma unroll
  for (int i = 0; i < 4; i++)
#pragma unroll
    for (int j = 0; j < 2; j++) acc[i][j] = (f32x4){0.f, 0.f, 0.f, 0.f};

  const int srr8 = lane >> 3, sq3 = lane & 7;

  auto stage = [&](int ks, int bufi) {
#pragma unroll
    for (int it = 0; it < 4; it++) {
      int r = w * 32 + it * 8 + srr8;
      int g = (sq3 - r) & 7;
      GLD16(A + (size_t)(bm + r) * K + ks * 64 + g * 8,
            &As[bufi][(w * 32 + it * 8) * 64]);
    }
#pragma unroll
    for (int it = 0; it < 2; it++) {
      int r = w * 16 + it * 8 + srr8;
      int g = (sq3 - r) & 7;
      GLD16(Wm + (size_t)(bn + r) * K + ks * 64 + g * 8,
            &Bs[bufi][(w * 16 + it * 8) * 64]);
    }
  };

  const int NKS = K >> 6;  // 8
  stage(0, 0);

  for (int ks = 0; ks < NKS; ks++) {
    __syncthreads();  // drains GLDs for buf cur + prior reads of buf nxt
    const int cur = ks & 1;
    if (ks + 1 < NKS) stage(ks + 1, cur ^ 1);
#pragma unroll
    for (int kk = 0; kk < 2; kk++) {
      short8 af[4], bf[2];
#pragma unroll
      for (int nt = 0; nt < 4; nt++) {
        int r = wm + nt * 16 + l15;
        af[nt] = *(const short8*)&As[cur][r * 64 + (((kk * 4 + lq) + r) & 7) * 8];
      }
#pragma unroll
      for (int j = 0; j < 2; j++) {
        int c = wn + j * 16 + l15;
        bf[j] = *(const short8*)&Bs[cur][c * 64 + (((kk * 4 + lq) + c) & 7) * 8];
      }
#pragma unroll
      for (int i = 0; i < 4; i++)
#pragma unroll
        for (int j = 0; j < 2; j++)
          acc[i][j] = __builtin_amdgcn_mfma_f32_16x16x32_bf16(
              af[i], bf[j], acc[i][j], 0, 0, 0);
    }
  }

  if (EPI == 1) {
#pragma unroll
    for (int i = 0; i < 4; i++) {
#pragma unroll
      for (int j = 0; j < 2; j++) {
        int c = bn + wn + j * 16 + l15;
        float bv = bias[c];
#pragma unroll
        for (int r = 0; r < 4; r++) {
          int m = bm + wm + i * 16 + lq * 4 + r;
          float v = acc[i][j][r] + bv;
          ((ushort*)outv)[(size_t)m * N + c] = f2bf(v);
        }
      }
    }
  } else {
    // Phase 1: acc(+bias+resid) -> Cs[c][m], float4 chunks XOR-swizzled.
#pragma unroll
    for (int i = 0; i < 4; i++) {
#pragma unroll
      for (int j = 0; j < 2; j++) {
        int c_l = wn + j * 16 + l15;
        int m_l = wm + i * 16 + lq * 4;
        float bv = bias[bn + c_l];
        f32x4 vv;
#pragma unroll
        for (int r = 0; r < 4; r++) {
          int m = bm + m_l + r;
          vv[r] = acc[i][j][r] + bv + bf2f(resid[(size_t)m * C_ + bn + c_l]);
        }
        int phys = (m_l >> 2) ^ (c_l & 31);
        *(f32x4*)&Cs[c_l * 128 + phys * 4] = vv;
      }
    }
    __syncthreads();
    // Phase 2: per c-row contiguous 512B stores (dwordx4, 32 lanes/row).
    const int b = bm >> 10, s0 = bm & (HW_ - 1);
    const int l5 = tid & 31;
    const int rr = tid >> 5;  // 0..7
    float* outp = (float*)outv;
#pragma unroll
    for (int pass = 0; pass < 8; pass++) {
      int row = rr + pass * 8;  // local c in [0,64)
      int phys = l5 ^ (row & 31);
      f32x4 vv = *(const f32x4*)&Cs[row * 128 + phys * 4];
      *(f32x4*)&outp[((size_t)(b * C_ + bn + row)) * HW_ + s0 + l5 * 4] = vv;
    }
  }
}

// -------------------------------------------------------------------------
// K3: MFMA flash attention, 32 queries/wave (128q/block, grid 512),
// bh-minor XCD-local order. K=32 PV via fragment concatenation.
// s_setprio(1) wraps the QK and PV MFMA clusters: the block's 4 waves
// drift through {QK, softmax, PV} phases independently between per-tile
// barriers -> scheduler favors the MFMA-issuing wave (m191 precedent).
__global__ __launch_bounds__(256) void attn_mfma_kernel(
    const ushort* __restrict__ qkv, const ushort* __restrict__ vt,
    const float* __restrict__ qsum, const float* __restrict__ ksum,
    const float* __restrict__ temp, ushort* __restrict__ o) {
  __shared__ alignas(16) ushort Ks[2][64 * 64];   // [key][d], chunk-swizzled
  __shared__ alignas(16) ushort Vts[2][64 * 64];  // [d][key], chunk-swizzled
  __shared__ float sc_lds[64];

  const int tid = threadIdx.x;
  const int w = tid >> 6, lane = tid & 63;
  const int quad = lane >> 4, lcol = lane & 15;
  const int bh = blockIdx.x & 63;   // XCD-locality: bh determines XCD
  const int qt = blockIdx.x >> 6;   // 0..7
  const int b = bh >> 3, h = bh & 7;
  const int q0 = qt * 128;

  if (tid < 64) {
    float qs = qsum[b * 512 + h * 64 + tid];
    float ks = ksum[b * 512 + h * 64 + tid];
    float iq = 1.0f / fmaxf(sqrtf(qs), 1e-12f);
    float ik = 1.0f / fmaxf(sqrtf(ks), 1e-12f);
    sc_lds[tid] = iq * ik * temp[h] * 1.44269504088896340736f;  // fold log2e
  }

  const ushort* kg = qkv + (size_t)b * HW_ * C3_ + C_ + h * 64;
  const ushort* vg = vt + (size_t)(bh * 64) * HW_;

  // staging: 256 threads x 2 iters cover 64 rows x 8 chunks (of 8 bf16)
  const int srow0 = tid >> 3;  // 0..31
  const int sc = tid & 7;

  // prologue: stage tile 0 into buffer 0
#pragma unroll
  for (int it = 0; it < 2; it++) {
    int row = srow0 + it * 32;
    int scg = sc ^ (row & 7);
    GLD16(kg + (size_t)row * C3_ + scg * 8, &Ks[0][w * 512 + it * 2048]);
    GLD16(vg + (size_t)row * HW_ + scg * 8, &Vts[0][w * 512 + it * 2048]);
  }
  __syncthreads();

  // Q fragments for both q-groups (B-operand of S^T = K·Q^T), scales folded.
  short8 qf[2][2];
#pragma unroll
  for (int qg = 0; qg < 2; qg++) {
    const int m = q0 + w * 32 + qg * 16 + lcol;
    const ushort* qrow = qkv + ((size_t)(b * HW_ + m)) * C3_ + h * 64;
#pragma unroll
    for (int kc = 0; kc < 2; kc++) {
      ushort8 q8 = *(const ushort8*)&qrow[kc * 32 + quad * 8];
      union { short8 v; ushort u[8]; } pk;
#pragma unroll
      for (int j = 0; j < 8; j++) {
        int d = kc * 32 + quad * 8 + j;
        pk.u[j] = f2bf(bf2f(q8[j]) * sc_lds[d]);
      }
      qf[qg][kc] = pk.v;
    }
  }

  f32x4 ot[2][4];
#pragma unroll
  for (int qg = 0; qg < 2; qg++)
#pragma unroll
    for (int dt = 0; dt < 4; dt++) ot[qg][dt] = (f32x4){0.f, 0.f, 0.f, 0.f};
  float lsum[2] = {0.f, 0.f};

  for (int kt = 0; kt < 16; kt++) {
    if (kt > 0) __syncthreads();  // drains GLD(kt) + prior buffer reads
    const int cur = kt & 1;
    if (kt + 1 < 16) {
      const int nxt = cur ^ 1;
#pragma unroll
      for (int it = 0; it < 2; it++) {
        int row = srow0 + it * 32;
        int scg = sc ^ (row & 7);
        GLD16(kg + (size_t)((kt + 1) * 64 + row) * C3_ + scg * 8,
              &Ks[nxt][w * 512 + it * 2048]);
        GLD16(vg + (size_t)row * HW_ + (kt + 1) * 64 + scg * 8,
              &Vts[nxt][w * 512 + it * 2048]);
      }
    }

    // S^T = K·Q^T for both q-groups; each K fragment read used twice
    f32x4 sfr[2][4];
#pragma unroll
    for (int qg = 0; qg < 2; qg++)
#pragma unroll
      for (int nt = 0; nt < 4; nt++) sfr[qg][nt] = (f32x4){0.f, 0.f, 0.f, 0.f};
    __builtin_amdgcn_s_setprio(1);
#pragma unroll
    for (int kc = 0; kc < 2; kc++) {
#pragma unroll
      for (int nt = 0; nt < 4; nt++) {
        int row = nt * 16 + lcol;
        short8 kf = *(const short8*)
            &Ks[cur][row * 64 + (((kc * 4 + quad) ^ (row & 7)) * 8)];
        sfr[0][nt] = __builtin_amdgcn_mfma_f32_16x16x32_bf16(kf, qf[0][kc],
                                                             sfr[0][nt], 0, 0, 0);
        sfr[1][nt] = __builtin_amdgcn_mfma_f32_16x16x32_bf16(kf, qf[1][kc],
                                                             sfr[1][nt], 0, 0, 0);
      }
    }
    __builtin_amdgcn_s_setprio(0);

    // exp2 + per-lane sum + pack P pairs via cvt_pk
    unsigned pu[2][4][2];
#pragma unroll
    for (int qg = 0; qg < 2; qg++) {
#pragma unroll
      for (int nt = 0; nt < 4; nt++) {
        float f0 = fast_exp2(sfr[qg][nt][0]);
        float f1 = fast_exp2(sfr[qg][nt][1]);
        float f2 = fast_exp2(sfr[qg][nt][2]);
        float f3 = fast_exp2(sfr[qg][nt][3]);
        lsum[qg] += f0 + f1 + f2 + f3;
        pu[qg][nt][0] = cvt_pk_bf16(f0, f1);
        pu[qg][nt][1] = cvt_pk_bf16(f2, f3);
      }
    }

    // O^T += V^T · P^T with K=32 MFMA (fragment concat, register-local).
    __builtin_amdgcn_s_setprio(1);
#pragma unroll
    for (int ntp = 0; ntp < 2; ntp++) {
      union { unsigned u[4]; short8 v; } pf0, pf1;
      pf0.u[0] = pu[0][2 * ntp][0];
      pf0.u[1] = pu[0][2 * ntp][1];
      pf0.u[2] = pu[0][2 * ntp + 1][0];
      pf0.u[3] = pu[0][2 * ntp + 1][1];
      pf1.u[0] = pu[1][2 * ntp][0];
      pf1.u[1] = pu[1][2 * ntp][1];
      pf1.u[2] = pu[1][2 * ntp + 1][0];
      pf1.u[3] = pu[1][2 * ntp + 1][1];
      int key0 = (2 * ntp) * 16 + quad * 4;
      int key1 = (2 * ntp + 1) * 16 + quad * 4;
#pragma unroll
      for (int dt = 0; dt < 4; dt++) {
        int d = dt * 16 + lcol;
        short4v v0 = *(const short4v*)
            &Vts[cur][d * 64 + (((key0 >> 3) ^ (d & 7)) * 8) + (key0 & 7)];
        short4v v1 = *(const short4v*)
            &Vts[cur][d * 64 + (((key1 >> 3) ^ (d & 7)) * 8) + (key1 & 7)];
        short8 vf = {v0[0], v0[1], v0[2], v0[3], v1[0], v1[1], v1[2], v1[3]};
        ot[0][dt] = __builtin_amdgcn_mfma_f32_16x16x32_bf16(vf, pf0.v,
                                                            ot[0][dt], 0, 0, 0);
        ot[1][dt] = __builtin_amdgcn_mfma_f32_16x16x32_bf16(vf, pf1.v,
                                                            ot[1][dt], 0, 0, 0);
      }
    }
    __builtin_amdgcn_s_setprio(0);
  }

#pragma unroll
  for (int qg = 0; qg < 2; qg++) {
    float s = lsum[qg];
    s += __shfl_xor(s, 16);
    s += __shfl_xor(s, 32);
    const float inv = 1.0f / s;
    const int m = q0 + w * 32 + qg * 16 + lcol;
    ushort* orow = o + ((size_t)(b * HW_ + m)) * C_ + h * 64;
#pragma unroll
    for (int dt = 0; dt < 4; dt++) {
      union { unsigned u[2]; ushort4_t s4; } pu2;
      pu2.u[0] = cvt_pk_bf16(ot[qg][dt][0] * inv, ot[qg][dt][1] * inv);
      pu2.u[1] = cvt_pk_bf16(ot[qg][dt][2] * inv, ot[qg][dt][3] * inv);
      *(ushort4_t*)&orow[dt * 16 + quad * 4] = pu2.s4;
    }
  }
}

// -------------------------------------------------------------------------
// K4 (fused): proj GEMM + bias + LayerNorm + residual(xT) -> y_bf.
// 16 tokens x 512 ch per block, grid 512 -> 2 blocks/CU.
__global__ __launch_bounds__(512) void gemm_proj_ln(
    const ushort* __restrict__ A, const ushort* __restrict__ Wm,
    const float* __restrict__ bias, const float* __restrict__ g,
    const float* __restrict__ bb, const ushort* __restrict__ resid,
    ushort* __restrict__ ybf) {
  __shared__ alignas(16) ushort As[2][16 * 32];
  __shared__ alignas(16) ushort Bs[2][512 * 32];
  __shared__ float red[8][16][2];
  const int bm = blockIdx.x * 16;
  const int tid = threadIdx.x;
  const int w = tid >> 6, lane = tid & 63;
  const int l15 = lane & 15, lq = lane >> 4;
  const int srr = lane >> 2, sq1 = lane & 3;

  f32x4 acc[4];
#pragma unroll
  for (int j = 0; j < 4; j++) acc[j] = (f32x4){0.f, 0.f, 0.f, 0.f};

  auto stage = [&](int kt, int bufi) {
#pragma unroll
    for (int it = 0; it < 4; it++) {
      int r = it * 128 + w * 16 + srr;
      int q = (sq1 - (r >> 1)) & 3;
      GLD16(Wm + (size_t)r * C_ + kt * 32 + q * 8,
            &Bs[bufi][(it * 128 + w * 16) * 32]);
    }
    if (w == 0) {
      int r = srr;  // 0..15
      int q = (sq1 - (r >> 1)) & 3;
      GLD16(A + (size_t)(bm + r) * C_ + kt * 32 + q * 8, &As[bufi][0]);
    }
  };

  stage(0, 0);

  for (int ks = 0; ks < 16; ks++) {
    __syncthreads();
    const int cur = ks & 1;
    if (ks + 1 < 16) stage(ks + 1, cur ^ 1);

    short8 af, bf[4];
    {
      int r = l15;
      af = *(const short8*)&As[cur][r * 32 + (((lq + (r >> 1)) & 3) * 8)];
    }
#pragma unroll
    for (int j = 0; j < 4; j++) {
      int c = w * 64 + j * 16 + l15;
      bf[j] = *(const short8*)&Bs[cur][c * 32 + (((lq + (c >> 1)) & 3) * 8)];
    }
#pragma unroll
    for (int j = 0; j < 4; j++)
      acc[j] = __builtin_amdgcn_mfma_f32_16x16x32_bf16(af, bf[j], acc[j],
                                                       0, 0, 0);
  }

  float bv[4];
#pragma unroll
  for (int j = 0; j < 4; j++) bv[j] = bias[w * 64 + j * 16 + l15];

  float s1v[4], s2v[4];
#pragma unroll
  for (int r = 0; r < 4; r++) {
    float a = 0.f, q2 = 0.f;
#pragma unroll
    for (int j = 0; j < 4; j++) {
      float v = acc[j][r] + bv[j];
      acc[j][r] = v;
      a += v;
      q2 += v * v;
    }
    s1v[r] = a;
    s2v[r] = q2;
  }
#pragma unroll
  for (int off = 1; off < 16; off <<= 1) {
#pragma unroll
    for (int r = 0; r < 4; r++) {
      s1v[r] += __shfl_xor(s1v[r], off);
      s2v[r] += __shfl_xor(s2v[r], off);
    }
  }
  if (l15 == 0) {
#pragma unroll
    for (int r = 0; r < 4; r++) {
      int tok = lq * 4 + r;
      red[w][tok][0] = s1v[r];
      red[w][tok][1] = s2v[r];
    }
  }
  __syncthreads();

  float gv[4], bbv[4];
#pragma unroll
  for (int j = 0; j < 4; j++) {
    gv[j] = g[w * 64 + j * 16 + l15];
    bbv[j] = bb[w * 64 + j * 16 + l15];
  }

#pragma unroll
  for (int r = 0; r < 4; r++) {
    int tok = lq * 4 + r;
    float su = 0.f, sq = 0.f;
#pragma unroll
    for (int ww = 0; ww < 8; ww++) {
      su += red[ww][tok][0];
      sq += red[ww][tok][1];
    }
    float mu = su * (1.0f / C_);
    float var = sq * (1.0f / C_) - mu * mu;
    float rstd = rsqrtf(var + 1e-5f);
    int m = bm + tok;
#pragma unroll
    for (int j = 0; j < 4; j++) {
      int c = w * 64 + j * 16 + l15;
      float y = (acc[j][r] - mu) * rstd * gv[j] + bbv[j] +
                bf2f(resid[(size_t)m * C_ + c]);
      ybf[(size_t)m * C_ + c] = f2bf(y);
    }
  }
}

// -------------------------------------------------------------------------
// K6: depthwise 3x3 SAME on bf16 y (token-major) -> bf16 out (+dw bias)
__global__ __launch_bounds__(256) void dwconv_kernel(
    const ushort* __restrict__ y, const float* __restrict__ w,
    const float* __restrict__ bias, ushort* __restrict__ out) {
  const int cg = threadIdx.x & 63, tg = threadIdx.x >> 6;
  const int c0 = cg * 8;
  float wreg[9][8], breg[8];
#pragma unroll
  for (int j = 0; j < 8; j++) {
    breg[j] = bias[c0 + j];
#pragma unroll
    for (int kk = 0; kk < 9; kk++) wreg[kk][j] = w[(c0 + j) * 9 + kk];
  }
  for (int i = 0; i < 4; i++) {
    int token = blockIdx.x * 16 + tg * 4 + i;
    int b = token >> 10, s = token & (HW_ - 1);
    int hh = s >> 5, ww = s & 31;
    float acc[8];
#pragma unroll
    for (int j = 0; j < 8; j++) acc[j] = breg[j];
#pragma unroll
    for (int ky = 0; ky < 3; ky++) {
      int yy = hh + ky - 1;
      if (yy < 0 || yy >= HH_) continue;
#pragma unroll
      for (int kx = 0; kx < 3; kx++) {
        int xx = ww + kx - 1;
        if (xx < 0 || xx >= WW_) continue;
        ushort8 v8 = *(const ushort8*)
            &y[((size_t)(b * HW_ + yy * 32 + xx)) * C_ + c0];
        const float* wk = wreg[ky * 3 + kx];
#pragma unroll
        for (int j = 0; j < 8; j++) acc[j] += wk[j] * bf2f(v8[j]);
      }
    }
    union { unsigned u[4]; ushort8 v; } pku;
    pku.u[0] = cvt_pk_bf16(acc[0], acc[1]);
    pku.u[1] = cvt_pk_bf16(acc[2], acc[3]);
    pku.u[2] = cvt_pk_bf16(acc[4], acc[5]);
    pku.u[3] = cvt_pk_bf16(acc[6], acc[7]);
    *(ushort8*)&out[(size_t)token * C_ + c0] = pku.v;
  }
}

// -------------------------------------------------------------------------
extern "C" void kernel_launch(void* const* d_in, const int* in_sizes, int n_in,
                              void* d_out, int out_size, void* d_ws,
                              size_t ws_size, hipStream_t stream) {
  const float* x = (const float*)d_in[0];
  const float* qkv_w = (const float*)d_in[1];
  const float* proj_w = (const float*)d_in[2];
  const float* proj_b = (const float*)d_in[3];
  const float* temperature = (const float*)d_in[4];
  const float* ln_g = (const float*)d_in[5];
  const float* ln_b = (const float*)d_in[6];
  const float* pos = (const float*)d_in[7];
  const float* dw_w = (const float*)d_in[8];
  const float* dw_b = (const float*)d_in[9];
  const float* pw_w = (const float*)d_in[10];
  const float* pw_b = (const float*)d_in[11];
  float* out = (float*)d_out;

  float* ws = (float*)d_ws;
  ushort* qkv_bf = (ushort*)ws;
  ushort* t_bf = (ushort*)(ws + (size_t)6 * 1024 * 1024);
  ushort* xT_bf = (ushort*)(ws + (size_t)12 * 1024 * 1024);
  ushort* wts = (ushort*)(ws + (size_t)14 * 1024 * 1024);
  ushort* qkvw_bf = wts;
  ushort* projw_bf = wts + 786432;
  ushort* pww_bf = wts + 1048576;
  float* sums = ws + (size_t)15 * 1024 * 1024;
  float* qsum = sums;
  float* ksum = sums + 4096;
  ushort* vtb = (ushort*)(ws + (size_t)16 * 1024 * 1024);

  const int M = BB_ * HW_;  // 8192 tokens

  // 1) prep: weights->bf16 (x4 vec), t/xT transpose, zero sums
  prep_kernel<<<2336, 256, 0, stream>>>(x, pos, qkv_w, proj_w, pw_w, t_bf,
                                        xT_bf, wts, sums);
  // 2) qkv GEMM (BK=64): q/k bf16 + norm-sums; V -> vt transposed
  gemm_qkv<<<dim3(C3_ / 128, M / 128), 256, 0, stream>>>(
      t_bf, qkvw_bf, qkv_bf, vtb, qsum, ksum);
  // 3) flash attention (128q/block, K=32 PV, setprio MFMA) -> attn_out
  attn_mfma_kernel<<<BB_ * NH_ * (HW_ / 128), 256, 0, stream>>>(
      qkv_bf, vtb, qsum, ksum, temperature, t_bf);
  // 4+5) fused proj GEMM + bias + LayerNorm + residual -> y_bf (over xT)
  gemm_proj_ln<<<M / 16, 512, 0, stream>>>(t_bf, projw_bf, proj_b, ln_g,
                                           ln_b, xT_bf, xT_bf);
  // 6) depthwise 3x3 on bf16 y -> dw_out (bf16, reuses t region)
  dwconv_kernel<<<M / 16, 256, 0, stream>>>(xT_bf, dw_w, dw_b, t_bf);
  // 7) pointwise GEMM (BK=64, dbuf) + pw_b + residual(y_bf), NCHW -> out
  gemm_n64<2><<<dim3(C_ / 64, M / 128), 256, 0, stream>>>(
      t_bf, pww_bf, pw_b, out, xT_bf, C_, C_);
}

// Round 7
// 192.162 us; speedup vs baseline: 1.0239x; 1.0239x over previous
//
#include <hip/hip_runtime.h>
#include <math.h>

// Problem constants
#define BB_ 8
#define C_ 512
#define C3_ 1536
#define HW_ 1024
#define NH_ 8
#define DH_ 64
#define HH_ 32
#define WW_ 32

typedef __attribute__((ext_vector_type(8))) short short8;
typedef __attribute__((ext_vector_type(4))) short short4v;
typedef __attribute__((ext_vector_type(8))) unsigned short ushort8;
typedef __attribute__((ext_vector_type(4))) unsigned short ushort4_t;
typedef __attribute__((ext_vector_type(4))) float f32x4;
typedef unsigned short ushort;

__device__ inline ushort f2bf(float f) {
  union { float f; unsigned u; } v;
  v.f = f;
  unsigned r = v.u + 0x7fffu + ((v.u >> 16) & 1u);
  return (ushort)(r >> 16);
}
__device__ inline float bf2f(ushort u) {
  union { unsigned u; float f; } v;
  v.u = ((unsigned)u) << 16;
  return v.f;
}

// One-instruction RNE pack of two f32 -> two bf16 (lo=a, hi=b).
__device__ inline unsigned cvt_pk_bf16(float a, float b) {
  unsigned r;
  asm("v_cvt_pk_bf16_f32 %0, %1, %2" : "=v"(r) : "v"(a), "v"(b));
  return r;
}

__device__ inline float fast_exp2(float x) {
#if __has_builtin(__builtin_amdgcn_exp2f)
  return __builtin_amdgcn_exp2f(x);
#else
  return exp2f(x);
#endif
}

#define GLD16(gptr, lptr)                                                     \
  __builtin_amdgcn_global_load_lds(                                           \
      (const __attribute__((address_space(1))) unsigned int*)(gptr),          \
      (__attribute__((address_space(3))) unsigned int*)(lptr), 16, 0, 0)

// -------------------------------------------------------------------------
// K1 (prep): fused weight-cvt (x4 vectorized) + x transpose(+pos) +
// qsum/ksum zeroing. Grid: 1024 transpose + 1280 wcvt + 32 sums = 2336.
__global__ __launch_bounds__(256) void prep_kernel(
    const float* __restrict__ x, const float* __restrict__ pos,
    const float* __restrict__ qkv_w, const float* __restrict__ proj_w,
    const float* __restrict__ pw_w, ushort* __restrict__ t,
    ushort* __restrict__ xT, ushort* __restrict__ wts,
    float* __restrict__ sums) {
  const int bid = blockIdx.x;
  const int tid = threadIdx.x;
  if (bid >= 2304) {
    sums[(bid - 2304) * 256 + tid] = 0.f;
    return;
  }
  if (bid >= 1024) {
    int i = ((bid - 1024) * 256 + tid) * 4;
    float4 v;
    if (i < 786432) v = *(const float4*)&qkv_w[i];
    else if (i < 1048576) v = *(const float4*)&proj_w[i - 786432];
    else v = *(const float4*)&pw_w[i - 1048576];
    union { unsigned u[2]; ushort4_t s; } o4;
    o4.u[0] = cvt_pk_bf16(v.x, v.y);
    o4.u[1] = cvt_pk_bf16(v.z, v.w);
    *(ushort4_t*)&wts[i] = o4.s;
    return;
  }
  __shared__ float tile[64][65];
  const int n0 = (bid & 15) * 64, c0 = ((bid >> 4) & 7) * 64, b = bid >> 7;
#pragma unroll
  for (int it = 0; it < 4; it++) {
    int c_l = (tid >> 4) + it * 16;
    int n_l4 = (tid & 15) * 4;
    float4 v = *(const float4*)&x[((size_t)(b * C_ + c0 + c_l)) * HW_ + n0 + n_l4];
    tile[c_l][n_l4 + 0] = v.x;
    tile[c_l][n_l4 + 1] = v.y;
    tile[c_l][n_l4 + 2] = v.z;
    tile[c_l][n_l4 + 3] = v.w;
  }
  __syncthreads();
#pragma unroll
  for (int it = 0; it < 4; it++) {
    int n_l = (tid >> 4) + it * 16;
    int c_l4 = (tid & 15) * 4;
    size_t token = (size_t)(b * HW_ + n0 + n_l);
    float4 pv = *(const float4*)&pos[(n0 + n_l) * C_ + c0 + c_l4];
    float xv0 = tile[c_l4 + 0][n_l], xv1 = tile[c_l4 + 1][n_l];
    float xv2 = tile[c_l4 + 2][n_l], xv3 = tile[c_l4 + 3][n_l];
    ushort4_t tb = {f2bf(xv0 + pv.x), f2bf(xv1 + pv.y), f2bf(xv2 + pv.z),
                    f2bf(xv3 + pv.w)};
    ushort4_t xb = {f2bf(xv0), f2bf(xv1), f2bf(xv2), f2bf(xv3)};
    *(ushort4_t*)&t[token * C_ + c0 + c_l4] = tb;
    *(ushort4_t*)&xT[token * C_ + c0 + c_l4] = xb;
  }
}

// -------------------------------------------------------------------------
// K2: qkv GEMM, BK=64 (8 K-steps). Row-swizzled 8-chunk LDS.
// XCD-locality remap: xcd = linear&7 (round-robin dispatch), each XCD owns
// 8 contiguous bm panels -> A panels (8x128KB) + B (1.5MB) fit its 4MB L2.
// Epilogue: q/k bf16 + norm-sums; V -> transposed bf16 into vt.
__global__ __launch_bounds__(256) void gemm_qkv(
    const ushort* __restrict__ A, const ushort* __restrict__ Wm,
    ushort* __restrict__ out, ushort* __restrict__ vt,
    float* __restrict__ qsum, float* __restrict__ ksum) {
  const int N = C3_, K = C_;
  __shared__ alignas(16) ushort As[128 * 64];
  __shared__ alignas(16) ushort Bs[128 * 64];
  const int f = blockIdx.y * gridDim.x + blockIdx.x;  // 0..767
  const int xcd = f & 7, idx = f >> 3;                // idx 0..95
  const int bm = (xcd * 8 + idx / 12) * 128;
  const int bn = (idx % 12) * 128;
  const int tid = threadIdx.x;
  const int w = tid >> 6, lane = tid & 63;
  const int wm = 64 * (w & 1), wn = 64 * (w >> 1);
  const int l15 = lane & 15, lq = lane >> 4;

  f32x4 acc[4][4];
#pragma unroll
  for (int i = 0; i < 4; i++)
#pragma unroll
    for (int j = 0; j < 4; j++) acc[i][j] = (f32x4){0.f, 0.f, 0.f, 0.f};

  const int srr8 = lane >> 3, sq3 = lane & 7;

  for (int k0 = 0; k0 < K; k0 += 64) {
    __syncthreads();
#pragma unroll
    for (int it = 0; it < 4; it++) {
      int r = w * 32 + it * 8 + srr8;
      int g = (sq3 - r) & 7;
      GLD16(A + (size_t)(bm + r) * K + k0 + g * 8, &As[(w * 32 + it * 8) * 64]);
      GLD16(Wm + (size_t)(bn + r) * K + k0 + g * 8, &Bs[(w * 32 + it * 8) * 64]);
    }
    __syncthreads();
#pragma unroll
    for (int kk = 0; kk < 2; kk++) {
      short8 af[4], bf[4];
#pragma unroll
      for (int nt = 0; nt < 4; nt++) {
        int r = wm + nt * 16 + l15;
        af[nt] = *(const short8*)&As[r * 64 + (((kk * 4 + lq) + r) & 7) * 8];
        int c = wn + nt * 16 + l15;
        bf[nt] = *(const short8*)&Bs[c * 64 + (((kk * 4 + lq) + c) & 7) * 8];
      }
#pragma unroll
      for (int i = 0; i < 4; i++)
#pragma unroll
        for (int j = 0; j < 4; j++)
          acc[i][j] = __builtin_amdgcn_mfma_f32_16x16x32_bf16(
              af[i], bf[j], acc[i][j], 0, 0, 0);
    }
  }

  const int b = bm >> 10;
  if (bn < 1024) {
#pragma unroll
    for (int j = 0; j < 4; j++) {
      int c = bn + wn + j * 16 + l15;
      float ss = 0.f;
#pragma unroll
      for (int i = 0; i < 4; i++) {
#pragma unroll
        for (int r = 0; r < 4; r++) {
          int m = bm + wm + i * 16 + lq * 4 + r;
          float v = acc[i][j][r];
          ss += v * v;
          out[(size_t)m * N + c] = f2bf(v);
        }
      }
      ss += __shfl_xor(ss, 16);
      ss += __shfl_xor(ss, 32);
      if (lq == 0) {
        if (c < 512) atomicAdd(&qsum[b * 512 + c], ss);
        else atomicAdd(&ksum[b * 512 + c - 512], ss);
      }
    }
  } else {
#pragma unroll
    for (int j = 0; j < 4; j++) {
      int c = bn + wn + j * 16 + l15;
      int hd = c - 1024;
      ushort* vrow = vt + ((size_t)(b * 512 + hd)) * HW_;
#pragma unroll
      for (int i = 0; i < 4; i++) {
        int n0 = (bm & 1023) + wm + i * 16 + lq * 4;
        union { unsigned u[2]; ushort4_t s; } pu;
        pu.u[0] = cvt_pk_bf16(acc[i][j][0], acc[i][j][1]);
        pu.u[1] = cvt_pk_bf16(acc[i][j][2], acc[i][j][3]);
        *(ushort4_t*)&vrow[n0] = pu.s;
      }
    }
  }
}

// -------------------------------------------------------------------------
// bf16 MFMA GEMM 128x64 tiles, BK=64 (8 K-steps), single-buffered (R5).
// XCD-locality remap (gy%8==0): each XCD owns gy/8 contiguous bm panels.
// EPI 2 (pointwise conv): f32 +bias +resid(bf16), NCHW via swizzled Cs.
template <int EPI>
__global__ __launch_bounds__(256) void gemm_n64(
    const ushort* __restrict__ A, const ushort* __restrict__ Wm,
    const float* __restrict__ bias, void* __restrict__ outv,
    const ushort* __restrict__ resid, int N, int K) {
  __shared__ alignas(16) ushort As[128 * 64];
  __shared__ alignas(16) ushort Bs[64 * 64];
  __shared__ alignas(16) float Cs[EPI == 2 ? 64 * 128 : 4];
  const int f = blockIdx.y * gridDim.x + blockIdx.x;
  const int xcd = f & 7, idx = f >> 3;
  const int nbx = gridDim.x;
  const int bm = (xcd * (gridDim.y >> 3) + idx / nbx) * 128;
  const int bn = (idx % nbx) * 64;
  const int tid = threadIdx.x;
  const int w = tid >> 6, lane = tid & 63;
  const int wm = 64 * (w & 1), wn = 32 * (w >> 1);
  const int l15 = lane & 15, lq = lane >> 4;

  f32x4 acc[4][2];
#pragma unroll
  for (int i = 0; i < 4; i++)
#pragma unroll
    for (int j = 0; j < 2; j++) acc[i][j] = (f32x4){0.f, 0.f, 0.f, 0.f};

  const int srr8 = lane >> 3, sq3 = lane & 7;

  for (int k0 = 0; k0 < K; k0 += 64) {
    __syncthreads();
#pragma unroll
    for (int it = 0; it < 4; it++) {
      int r = w * 32 + it * 8 + srr8;
      int g = (sq3 - r) & 7;
      GLD16(A + (size_t)(bm + r) * K + k0 + g * 8, &As[(w * 32 + it * 8) * 64]);
    }
#pragma unroll
    for (int it = 0; it < 2; it++) {
      int r = w * 16 + it * 8 + srr8;
      int g = (sq3 - r) & 7;
      GLD16(Wm + (size_t)(bn + r) * K + k0 + g * 8, &Bs[(w * 16 + it * 8) * 64]);
    }
    __syncthreads();
#pragma unroll
    for (int kk = 0; kk < 2; kk++) {
      short8 af[4], bf[2];
#pragma unroll
      for (int nt = 0; nt < 4; nt++) {
        int r = wm + nt * 16 + l15;
        af[nt] = *(const short8*)&As[r * 64 + (((kk * 4 + lq) + r) & 7) * 8];
      }
#pragma unroll
      for (int j = 0; j < 2; j++) {
        int c = wn + j * 16 + l15;
        bf[j] = *(const short8*)&Bs[c * 64 + (((kk * 4 + lq) + c) & 7) * 8];
      }
#pragma unroll
      for (int i = 0; i < 4; i++)
#pragma unroll
        for (int j = 0; j < 2; j++)
          acc[i][j] = __builtin_amdgcn_mfma_f32_16x16x32_bf16(
              af[i], bf[j], acc[i][j], 0, 0, 0);
    }
  }

  if (EPI == 1) {
#pragma unroll
    for (int i = 0; i < 4; i++) {
#pragma unroll
      for (int j = 0; j < 2; j++) {
        int c = bn + wn + j * 16 + l15;
        float bv = bias[c];
#pragma unroll
        for (int r = 0; r < 4; r++) {
          int m = bm + wm + i * 16 + lq * 4 + r;
          float v = acc[i][j][r] + bv;
          ((ushort*)outv)[(size_t)m * N + c] = f2bf(v);
        }
      }
    }
  } else {
    // Phase 1: acc(+bias+resid) -> Cs[c][m], float4 chunks XOR-swizzled.
#pragma unroll
    for (int i = 0; i < 4; i++) {
#pragma unroll
      for (int j = 0; j < 2; j++) {
        int c_l = wn + j * 16 + l15;
        int m_l = wm + i * 16 + lq * 4;
        float bv = bias[bn + c_l];
        f32x4 vv;
#pragma unroll
        for (int r = 0; r < 4; r++) {
          int m = bm + m_l + r;
          vv[r] = acc[i][j][r] + bv + bf2f(resid[(size_t)m * C_ + bn + c_l]);
        }
        int phys = (m_l >> 2) ^ (c_l & 31);
        *(f32x4*)&Cs[c_l * 128 + phys * 4] = vv;
      }
    }
    __syncthreads();
    // Phase 2: per c-row contiguous 512B stores (dwordx4, 32 lanes/row).
    const int b = bm >> 10, s0 = bm & (HW_ - 1);
    const int l5 = tid & 31;
    const int rr = tid >> 5;  // 0..7
    float* outp = (float*)outv;
#pragma unroll
    for (int pass = 0; pass < 8; pass++) {
      int row = rr + pass * 8;  // local c in [0,64)
      int phys = l5 ^ (row & 31);
      f32x4 vv = *(const f32x4*)&Cs[row * 128 + phys * 4];
      *(f32x4*)&outp[((size_t)(b * C_ + bn + row)) * HW_ + s0 + l5 * 4] = vv;
    }
  }
}

// -------------------------------------------------------------------------
// K3: MFMA flash attention, 32 queries/wave (128q/block, grid 512),
// bh-minor XCD-local order. K=32 PV via fragment concatenation (R5 state;
// setprio reverted — waves are barrier-synced per tile, m190 regime).
__global__ __launch_bounds__(256) void attn_mfma_kernel(
    const ushort* __restrict__ qkv, const ushort* __restrict__ vt,
    const float* __restrict__ qsum, const float* __restrict__ ksum,
    const float* __restrict__ temp, ushort* __restrict__ o) {
  __shared__ alignas(16) ushort Ks[2][64 * 64];   // [key][d], chunk-swizzled
  __shared__ alignas(16) ushort Vts[2][64 * 64];  // [d][key], chunk-swizzled
  __shared__ float sc_lds[64];

  const int tid = threadIdx.x;
  const int w = tid >> 6, lane = tid & 63;
  const int quad = lane >> 4, lcol = lane & 15;
  const int bh = blockIdx.x & 63;   // XCD-locality: bh determines XCD
  const int qt = blockIdx.x >> 6;   // 0..7
  const int b = bh >> 3, h = bh & 7;
  const int q0 = qt * 128;

  if (tid < 64) {
    float qs = qsum[b * 512 + h * 64 + tid];
    float ks = ksum[b * 512 + h * 64 + tid];
    float iq = 1.0f / fmaxf(sqrtf(qs), 1e-12f);
    float ik = 1.0f / fmaxf(sqrtf(ks), 1e-12f);
    sc_lds[tid] = iq * ik * temp[h] * 1.44269504088896340736f;  // fold log2e
  }

  const ushort* kg = qkv + (size_t)b * HW_ * C3_ + C_ + h * 64;
  const ushort* vg = vt + (size_t)(bh * 64) * HW_;

  // staging: 256 threads x 2 iters cover 64 rows x 8 chunks (of 8 bf16)
  const int srow0 = tid >> 3;  // 0..31
  const int sc = tid & 7;

  // prologue: stage tile 0 into buffer 0
#pragma unroll
  for (int it = 0; it < 2; it++) {
    int row = srow0 + it * 32;
    int scg = sc ^ (row & 7);
    GLD16(kg + (size_t)row * C3_ + scg * 8, &Ks[0][w * 512 + it * 2048]);
    GLD16(vg + (size_t)row * HW_ + scg * 8, &Vts[0][w * 512 + it * 2048]);
  }
  __syncthreads();

  // Q fragments for both q-groups (B-operand of S^T = K·Q^T), scales folded.
  short8 qf[2][2];
#pragma unroll
  for (int qg = 0; qg < 2; qg++) {
    const int m = q0 + w * 32 + qg * 16 + lcol;
    const ushort* qrow = qkv + ((size_t)(b * HW_ + m)) * C3_ + h * 64;
#pragma unroll
    for (int kc = 0; kc < 2; kc++) {
      ushort8 q8 = *(const ushort8*)&qrow[kc * 32 + quad * 8];
      union { short8 v; ushort u[8]; } pk;
#pragma unroll
      for (int j = 0; j < 8; j++) {
        int d = kc * 32 + quad * 8 + j;
        pk.u[j] = f2bf(bf2f(q8[j]) * sc_lds[d]);
      }
      qf[qg][kc] = pk.v;
    }
  }

  f32x4 ot[2][4];
#pragma unroll
  for (int qg = 0; qg < 2; qg++)
#pragma unroll
    for (int dt = 0; dt < 4; dt++) ot[qg][dt] = (f32x4){0.f, 0.f, 0.f, 0.f};
  float lsum[2] = {0.f, 0.f};

  for (int kt = 0; kt < 16; kt++) {
    if (kt > 0) __syncthreads();  // drains GLD(kt) + prior buffer reads
    const int cur = kt & 1;
    if (kt + 1 < 16) {
      const int nxt = cur ^ 1;
#pragma unroll
      for (int it = 0; it < 2; it++) {
        int row = srow0 + it * 32;
        int scg = sc ^ (row & 7);
        GLD16(kg + (size_t)((kt + 1) * 64 + row) * C3_ + scg * 8,
              &Ks[nxt][w * 512 + it * 2048]);
        GLD16(vg + (size_t)row * HW_ + (kt + 1) * 64 + scg * 8,
              &Vts[nxt][w * 512 + it * 2048]);
      }
    }

    // S^T = K·Q^T for both q-groups; each K fragment read used twice
    f32x4 sfr[2][4];
#pragma unroll
    for (int qg = 0; qg < 2; qg++)
#pragma unroll
      for (int nt = 0; nt < 4; nt++) sfr[qg][nt] = (f32x4){0.f, 0.f, 0.f, 0.f};
#pragma unroll
    for (int kc = 0; kc < 2; kc++) {
#pragma unroll
      for (int nt = 0; nt < 4; nt++) {
        int row = nt * 16 + lcol;
        short8 kf = *(const short8*)
            &Ks[cur][row * 64 + (((kc * 4 + quad) ^ (row & 7)) * 8)];
        sfr[0][nt] = __builtin_amdgcn_mfma_f32_16x16x32_bf16(kf, qf[0][kc],
                                                             sfr[0][nt], 0, 0, 0);
        sfr[1][nt] = __builtin_amdgcn_mfma_f32_16x16x32_bf16(kf, qf[1][kc],
                                                             sfr[1][nt], 0, 0, 0);
      }
    }

    // exp2 + per-lane sum + pack P pairs via cvt_pk
    unsigned pu[2][4][2];
#pragma unroll
    for (int qg = 0; qg < 2; qg++) {
#pragma unroll
      for (int nt = 0; nt < 4; nt++) {
        float f0 = fast_exp2(sfr[qg][nt][0]);
        float f1 = fast_exp2(sfr[qg][nt][1]);
        float f2 = fast_exp2(sfr[qg][nt][2]);
        float f3 = fast_exp2(sfr[qg][nt][3]);
        lsum[qg] += f0 + f1 + f2 + f3;
        pu[qg][nt][0] = cvt_pk_bf16(f0, f1);
        pu[qg][nt][1] = cvt_pk_bf16(f2, f3);
      }
    }

    // O^T += V^T · P^T with K=32 MFMA (fragment concat, register-local).
#pragma unroll
    for (int ntp = 0; ntp < 2; ntp++) {
      union { unsigned u[4]; short8 v; } pf0, pf1;
      pf0.u[0] = pu[0][2 * ntp][0];
      pf0.u[1] = pu[0][2 * ntp][1];
      pf0.u[2] = pu[0][2 * ntp + 1][0];
      pf0.u[3] = pu[0][2 * ntp + 1][1];
      pf1.u[0] = pu[1][2 * ntp][0];
      pf1.u[1] = pu[1][2 * ntp][1];
      pf1.u[2] = pu[1][2 * ntp + 1][0];
      pf1.u[3] = pu[1][2 * ntp + 1][1];
      int key0 = (2 * ntp) * 16 + quad * 4;
      int key1 = (2 * ntp + 1) * 16 + quad * 4;
#pragma unroll
      for (int dt = 0; dt < 4; dt++) {
        int d = dt * 16 + lcol;
        short4v v0 = *(const short4v*)
            &Vts[cur][d * 64 + (((key0 >> 3) ^ (d & 7)) * 8) + (key0 & 7)];
        short4v v1 = *(const short4v*)
            &Vts[cur][d * 64 + (((key1 >> 3) ^ (d & 7)) * 8) + (key1 & 7)];
        short8 vf = {v0[0], v0[1], v0[2], v0[3], v1[0], v1[1], v1[2], v1[3]};
        ot[0][dt] = __builtin_amdgcn_mfma_f32_16x16x32_bf16(vf, pf0.v,
                                                            ot[0][dt], 0, 0, 0);
        ot[1][dt] = __builtin_amdgcn_mfma_f32_16x16x32_bf16(vf, pf1.v,
                                                            ot[1][dt], 0, 0, 0);
      }
    }
  }

#pragma unroll
  for (int qg = 0; qg < 2; qg++) {
    float s = lsum[qg];
    s += __shfl_xor(s, 16);
    s += __shfl_xor(s, 32);
    const float inv = 1.0f / s;
    const int m = q0 + w * 32 + qg * 16 + lcol;
    ushort* orow = o + ((size_t)(b * HW_ + m)) * C_ + h * 64;
#pragma unroll
    for (int dt = 0; dt < 4; dt++) {
      union { unsigned u[2]; ushort4_t s4; } pu2;
      pu2.u[0] = cvt_pk_bf16(ot[qg][dt][0] * inv, ot[qg][dt][1] * inv);
      pu2.u[1] = cvt_pk_bf16(ot[qg][dt][2] * inv, ot[qg][dt][3] * inv);
      *(ushort4_t*)&orow[dt * 16 + quad * 4] = pu2.s4;
    }
  }
}

// -------------------------------------------------------------------------
// K4 (fused): proj GEMM + bias + LayerNorm + residual(xT) -> y_bf.
// 16 tokens x 512 ch per block, grid 512 -> 2 blocks/CU.
__global__ __launch_bounds__(512) void gemm_proj_ln(
    const ushort* __restrict__ A, const ushort* __restrict__ Wm,
    const float* __restrict__ bias, const float* __restrict__ g,
    const float* __restrict__ bb, const ushort* __restrict__ resid,
    ushort* __restrict__ ybf) {
  __shared__ alignas(16) ushort As[2][16 * 32];
  __shared__ alignas(16) ushort Bs[2][512 * 32];
  __shared__ float red[8][16][2];
  const int bm = blockIdx.x * 16;
  const int tid = threadIdx.x;
  const int w = tid >> 6, lane = tid & 63;
  const int l15 = lane & 15, lq = lane >> 4;
  const int srr = lane >> 2, sq1 = lane & 3;

  f32x4 acc[4];
#pragma unroll
  for (int j = 0; j < 4; j++) acc[j] = (f32x4){0.f, 0.f, 0.f, 0.f};

  auto stage = [&](int kt, int bufi) {
#pragma unroll
    for (int it = 0; it < 4; it++) {
      int r = it * 128 + w * 16 + srr;
      int q = (sq1 - (r >> 1)) & 3;
      GLD16(Wm + (size_t)r * C_ + kt * 32 + q * 8,
            &Bs[bufi][(it * 128 + w * 16) * 32]);
    }
    if (w == 0) {
      int r = srr;  // 0..15
      int q = (sq1 - (r >> 1)) & 3;
      GLD16(A + (size_t)(bm + r) * C_ + kt * 32 + q * 8, &As[bufi][0]);
    }
  };

  stage(0, 0);

  for (int ks = 0; ks < 16; ks++) {
    __syncthreads();
    const int cur = ks & 1;
    if (ks + 1 < 16) stage(ks + 1, cur ^ 1);

    short8 af, bf[4];
    {
      int r = l15;
      af = *(const short8*)&As[cur][r * 32 + (((lq + (r >> 1)) & 3) * 8)];
    }
#pragma unroll
    for (int j = 0; j < 4; j++) {
      int c = w * 64 + j * 16 + l15;
      bf[j] = *(const short8*)&Bs[cur][c * 32 + (((lq + (c >> 1)) & 3) * 8)];
    }
#pragma unroll
    for (int j = 0; j < 4; j++)
      acc[j] = __builtin_amdgcn_mfma_f32_16x16x32_bf16(af, bf[j], acc[j],
                                                       0, 0, 0);
  }

  float bv[4];
#pragma unroll
  for (int j = 0; j < 4; j++) bv[j] = bias[w * 64 + j * 16 + l15];

  float s1v[4], s2v[4];
#pragma unroll
  for (int r = 0; r < 4; r++) {
    float a = 0.f, q2 = 0.f;
#pragma unroll
    for (int j = 0; j < 4; j++) {
      float v = acc[j][r] + bv[j];
      acc[j][r] = v;
      a += v;
      q2 += v * v;
    }
    s1v[r] = a;
    s2v[r] = q2;
  }
#pragma unroll
  for (int off = 1; off < 16; off <<= 1) {
#pragma unroll
    for (int r = 0; r < 4; r++) {
      s1v[r] += __shfl_xor(s1v[r], off);
      s2v[r] += __shfl_xor(s2v[r], off);
    }
  }
  if (l15 == 0) {
#pragma unroll
    for (int r = 0; r < 4; r++) {
      int tok = lq * 4 + r;
      red[w][tok][0] = s1v[r];
      red[w][tok][1] = s2v[r];
    }
  }
  __syncthreads();

  float gv[4], bbv[4];
#pragma unroll
  for (int j = 0; j < 4; j++) {
    gv[j] = g[w * 64 + j * 16 + l15];
    bbv[j] = bb[w * 64 + j * 16 + l15];
  }

#pragma unroll
  for (int r = 0; r < 4; r++) {
    int tok = lq * 4 + r;
    float su = 0.f, sq = 0.f;
#pragma unroll
    for (int ww = 0; ww < 8; ww++) {
      su += red[ww][tok][0];
      sq += red[ww][tok][1];
    }
    float mu = su * (1.0f / C_);
    float var = sq * (1.0f / C_) - mu * mu;
    float rstd = rsqrtf(var + 1e-5f);
    int m = bm + tok;
#pragma unroll
    for (int j = 0; j < 4; j++) {
      int c = w * 64 + j * 16 + l15;
      float y = (acc[j][r] - mu) * rstd * gv[j] + bbv[j] +
                bf2f(resid[(size_t)m * C_ + c]);
      ybf[(size_t)m * C_ + c] = f2bf(y);
    }
  }
}

// -------------------------------------------------------------------------
// K6: depthwise 3x3 SAME on bf16 y (token-major) -> bf16 out (+dw bias)
__global__ __launch_bounds__(256) void dwconv_kernel(
    const ushort* __restrict__ y, const float* __restrict__ w,
    const float* __restrict__ bias, ushort* __restrict__ out) {
  const int cg = threadIdx.x & 63, tg = threadIdx.x >> 6;
  const int c0 = cg * 8;
  float wreg[9][8], breg[8];
#pragma unroll
  for (int j = 0; j < 8; j++) {
    breg[j] = bias[c0 + j];
#pragma unroll
    for (int kk = 0; kk < 9; kk++) wreg[kk][j] = w[(c0 + j) * 9 + kk];
  }
  for (int i = 0; i < 4; i++) {
    int token = blockIdx.x * 16 + tg * 4 + i;
    int b = token >> 10, s = token & (HW_ - 1);
    int hh = s >> 5, ww = s & 31;
    float acc[8];
#pragma unroll
    for (int j = 0; j < 8; j++) acc[j] = breg[j];
#pragma unroll
    for (int ky = 0; ky < 3; ky++) {
      int yy = hh + ky - 1;
      if (yy < 0 || yy >= HH_) continue;
#pragma unroll
      for (int kx = 0; kx < 3; kx++) {
        int xx = ww + kx - 1;
        if (xx < 0 || xx >= WW_) continue;
        ushort8 v8 = *(const ushort8*)
            &y[((size_t)(b * HW_ + yy * 32 + xx)) * C_ + c0];
        const float* wk = wreg[ky * 3 + kx];
#pragma unroll
        for (int j = 0; j < 8; j++) acc[j] += wk[j] * bf2f(v8[j]);
      }
    }
    union { unsigned u[4]; ushort8 v; } pku;
    pku.u[0] = cvt_pk_bf16(acc[0], acc[1]);
    pku.u[1] = cvt_pk_bf16(acc[2], acc[3]);
    pku.u[2] = cvt_pk_bf16(acc[4], acc[5]);
    pku.u[3] = cvt_pk_bf16(acc[6], acc[7]);
    *(ushort8*)&out[(size_t)token * C_ + c0] = pku.v;
  }
}

// -------------------------------------------------------------------------
extern "C" void kernel_launch(void* const* d_in, const int* in_sizes, int n_in,
                              void* d_out, int out_size, void* d_ws,
                              size_t ws_size, hipStream_t stream) {
  const float* x = (const float*)d_in[0];
  const float* qkv_w = (const float*)d_in[1];
  const float* proj_w = (const float*)d_in[2];
  const float* proj_b = (const float*)d_in[3];
  const float* temperature = (const float*)d_in[4];
  const float* ln_g = (const float*)d_in[5];
  const float* ln_b = (const float*)d_in[6];
  const float* pos = (const float*)d_in[7];
  const float* dw_w = (const float*)d_in[8];
  const float* dw_b = (const float*)d_in[9];
  const float* pw_w = (const float*)d_in[10];
  const float* pw_b = (const float*)d_in[11];
  float* out = (float*)d_out;

  float* ws = (float*)d_ws;
  ushort* qkv_bf = (ushort*)ws;
  ushort* t_bf = (ushort*)(ws + (size_t)6 * 1024 * 1024);
  ushort* xT_bf = (ushort*)(ws + (size_t)12 * 1024 * 1024);
  ushort* wts = (ushort*)(ws + (size_t)14 * 1024 * 1024);
  ushort* qkvw_bf = wts;
  ushort* projw_bf = wts + 786432;
  ushort* pww_bf = wts + 1048576;
  float* sums = ws + (size_t)15 * 1024 * 1024;
  float* qsum = sums;
  float* ksum = sums + 4096;
  ushort* vtb = (ushort*)(ws + (size_t)16 * 1024 * 1024);

  const int M = BB_ * HW_;  // 8192 tokens

  // 1) prep: weights->bf16 (x4 vec), t/xT transpose, zero sums
  prep_kernel<<<2336, 256, 0, stream>>>(x, pos, qkv_w, proj_w, pw_w, t_bf,
                                        xT_bf, wts, sums);
  // 2) qkv GEMM (BK=64, XCD-local bm): q/k bf16 + norm-sums; V -> vt
  gemm_qkv<<<dim3(C3_ / 128, M / 128), 256, 0, stream>>>(
      t_bf, qkvw_bf, qkv_bf, vtb, qsum, ksum);
  // 3) flash attention (128q/block, K=32 PV via fragment concat) -> attn_out
  attn_mfma_kernel<<<BB_ * NH_ * (HW_ / 128), 256, 0, stream>>>(
      qkv_bf, vtb, qsum, ksum, temperature, t_bf);
  // 4+5) fused proj GEMM + bias + LayerNorm + residual -> y_bf (over xT)
  gemm_proj_ln<<<M / 16, 512, 0, stream>>>(t_bf, projw_bf, proj_b, ln_g,
                                           ln_b, xT_bf, xT_bf);
  // 6) depthwise 3x3 on bf16 y -> dw_out (bf16, reuses t region)
  dwconv_kernel<<<M / 16, 256, 0, stream>>>(xT_bf, dw_w, dw_b, t_bf);
  // 7) pointwise GEMM (BK=64, XCD-local bm) + pw_b + residual, NCHW -> out
  gemm_n64<2><<<dim3(C_ / 64, M / 128), 256, 0, stream>>>(
      t_bf, pww_bf, pw_b, out, xT_bf, C_, C_);
}

// Round 8
// 190.698 us; speedup vs baseline: 1.0318x; 1.0077x over previous
//
#include <hip/hip_runtime.h>
#include <math.h>

// Problem constants
#define BB_ 8
#define C_ 512
#define C3_ 1536
#define HW_ 1024
#define NH_ 8
#define DH_ 64
#define HH_ 32
#define WW_ 32

typedef __attribute__((ext_vector_type(8))) short short8;
typedef __attribute__((ext_vector_type(4))) short short4v;
typedef __attribute__((ext_vector_type(8))) unsigned short ushort8;
typedef __attribute__((ext_vector_type(4))) unsigned short ushort4_t;
typedef __attribute__((ext_vector_type(4))) float f32x4;
typedef unsigned short ushort;

__device__ inline ushort f2bf(float f) {
  union { float f; unsigned u; } v;
  v.f = f;
  unsigned r = v.u + 0x7fffu + ((v.u >> 16) & 1u);
  return (ushort)(r >> 16);
}
__device__ inline float bf2f(ushort u) {
  union { unsigned u; float f; } v;
  v.u = ((unsigned)u) << 16;
  return v.f;
}

// One-instruction RNE pack of two f32 -> two bf16 (lo=a, hi=b).
__device__ inline unsigned cvt_pk_bf16(float a, float b) {
  unsigned r;
  asm("v_cvt_pk_bf16_f32 %0, %1, %2" : "=v"(r) : "v"(a), "v"(b));
  return r;
}

__device__ inline float fast_exp2(float x) {
#if __has_builtin(__builtin_amdgcn_exp2f)
  return __builtin_amdgcn_exp2f(x);
#else
  return exp2f(x);
#endif
}

#define GLD16(gptr, lptr)                                                     \
  __builtin_amdgcn_global_load_lds(                                           \
      (const __attribute__((address_space(1))) unsigned int*)(gptr),          \
      (__attribute__((address_space(3))) unsigned int*)(lptr), 16, 0, 0)

// -------------------------------------------------------------------------
// K1 (prep): fused weight-cvt (x4 vectorized) + x transpose(+pos) +
// qsum/ksum zeroing. Grid: 1024 transpose + 1280 wcvt + 32 sums = 2336.
__global__ __launch_bounds__(256) void prep_kernel(
    const float* __restrict__ x, const float* __restrict__ pos,
    const float* __restrict__ qkv_w, const float* __restrict__ proj_w,
    const float* __restrict__ pw_w, ushort* __restrict__ t,
    ushort* __restrict__ xT, ushort* __restrict__ wts,
    float* __restrict__ sums) {
  const int bid = blockIdx.x;
  const int tid = threadIdx.x;
  if (bid >= 2304) {
    sums[(bid - 2304) * 256 + tid] = 0.f;
    return;
  }
  if (bid >= 1024) {
    int i = ((bid - 1024) * 256 + tid) * 4;
    float4 v;
    if (i < 786432) v = *(const float4*)&qkv_w[i];
    else if (i < 1048576) v = *(const float4*)&proj_w[i - 786432];
    else v = *(const float4*)&pw_w[i - 1048576];
    union { unsigned u[2]; ushort4_t s; } o4;
    o4.u[0] = cvt_pk_bf16(v.x, v.y);
    o4.u[1] = cvt_pk_bf16(v.z, v.w);
    *(ushort4_t*)&wts[i] = o4.s;
    return;
  }
  __shared__ float tile[64][65];
  const int n0 = (bid & 15) * 64, c0 = ((bid >> 4) & 7) * 64, b = bid >> 7;
#pragma unroll
  for (int it = 0; it < 4; it++) {
    int c_l = (tid >> 4) + it * 16;
    int n_l4 = (tid & 15) * 4;
    float4 v = *(const float4*)&x[((size_t)(b * C_ + c0 + c_l)) * HW_ + n0 + n_l4];
    tile[c_l][n_l4 + 0] = v.x;
    tile[c_l][n_l4 + 1] = v.y;
    tile[c_l][n_l4 + 2] = v.z;
    tile[c_l][n_l4 + 3] = v.w;
  }
  __syncthreads();
#pragma unroll
  for (int it = 0; it < 4; it++) {
    int n_l = (tid >> 4) + it * 16;
    int c_l4 = (tid & 15) * 4;
    size_t token = (size_t)(b * HW_ + n0 + n_l);
    float4 pv = *(const float4*)&pos[(n0 + n_l) * C_ + c0 + c_l4];
    float xv0 = tile[c_l4 + 0][n_l], xv1 = tile[c_l4 + 1][n_l];
    float xv2 = tile[c_l4 + 2][n_l], xv3 = tile[c_l4 + 3][n_l];
    ushort4_t tb = {f2bf(xv0 + pv.x), f2bf(xv1 + pv.y), f2bf(xv2 + pv.z),
                    f2bf(xv3 + pv.w)};
    ushort4_t xb = {f2bf(xv0), f2bf(xv1), f2bf(xv2), f2bf(xv3)};
    *(ushort4_t*)&t[token * C_ + c0 + c_l4] = tb;
    *(ushort4_t*)&xT[token * C_ + c0 + c_l4] = xb;
  }
}

// -------------------------------------------------------------------------
// K2: qkv GEMM, BK=64 (8 K-steps). Row-swizzled 8-chunk LDS. XCD-local bm.
// q/k epilogue now stages the 128x128 bf16 tile through LDS (reusing
// As+Bs, chunk-swizzled phys=(c>>3)^(m&15)) -> contiguous ushort8 stores
// (was: 64 scalar 2B stores/lane). V -> transposed bf16 into vt.
__global__ __launch_bounds__(256) void gemm_qkv(
    const ushort* __restrict__ A, const ushort* __restrict__ Wm,
    ushort* __restrict__ out, ushort* __restrict__ vt,
    float* __restrict__ qsum, float* __restrict__ ksum) {
  const int N = C3_, K = C_;
  __shared__ alignas(16) ushort smem[2 * 128 * 64];
  ushort* As = smem;
  ushort* Bs = smem + 128 * 64;
  const int f = blockIdx.y * gridDim.x + blockIdx.x;  // 0..767
  const int xcd = f & 7, idx = f >> 3;                // idx 0..95
  const int bm = (xcd * 8 + idx / 12) * 128;
  const int bn = (idx % 12) * 128;
  const int tid = threadIdx.x;
  const int w = tid >> 6, lane = tid & 63;
  const int wm = 64 * (w & 1), wn = 64 * (w >> 1);
  const int l15 = lane & 15, lq = lane >> 4;

  f32x4 acc[4][4];
#pragma unroll
  for (int i = 0; i < 4; i++)
#pragma unroll
    for (int j = 0; j < 4; j++) acc[i][j] = (f32x4){0.f, 0.f, 0.f, 0.f};

  const int srr8 = lane >> 3, sq3 = lane & 7;

  for (int k0 = 0; k0 < K; k0 += 64) {
    __syncthreads();
#pragma unroll
    for (int it = 0; it < 4; it++) {
      int r = w * 32 + it * 8 + srr8;
      int g = (sq3 - r) & 7;
      GLD16(A + (size_t)(bm + r) * K + k0 + g * 8, &As[(w * 32 + it * 8) * 64]);
      GLD16(Wm + (size_t)(bn + r) * K + k0 + g * 8, &Bs[(w * 32 + it * 8) * 64]);
    }
    __syncthreads();
#pragma unroll
    for (int kk = 0; kk < 2; kk++) {
      short8 af[4], bf[4];
#pragma unroll
      for (int nt = 0; nt < 4; nt++) {
        int r = wm + nt * 16 + l15;
        af[nt] = *(const short8*)&As[r * 64 + (((kk * 4 + lq) + r) & 7) * 8];
        int c = wn + nt * 16 + l15;
        bf[nt] = *(const short8*)&Bs[c * 64 + (((kk * 4 + lq) + c) & 7) * 8];
      }
#pragma unroll
      for (int i = 0; i < 4; i++)
#pragma unroll
        for (int j = 0; j < 4; j++)
          acc[i][j] = __builtin_amdgcn_mfma_f32_16x16x32_bf16(
              af[i], bf[j], acc[i][j], 0, 0, 0);
    }
  }

  const int b = bm >> 10;
  if (bn < 1024) {
    __syncthreads();  // all LDS reads of As/Bs done before T reuse
    ushort* T = smem;  // 128m x 128c bf16, chunk-swizzled
#pragma unroll
    for (int j = 0; j < 4; j++) {
      int c_l = wn + j * 16 + l15;
      int c = bn + c_l;
      float ss = 0.f;
#pragma unroll
      for (int i = 0; i < 4; i++) {
#pragma unroll
        for (int r = 0; r < 4; r++) {
          int m_l = wm + i * 16 + lq * 4 + r;
          float v = acc[i][j][r];
          ss += v * v;
          T[m_l * 128 + (((c_l >> 3) ^ (m_l & 15)) << 3) + (c_l & 7)] =
              f2bf(v);
        }
      }
      ss += __shfl_xor(ss, 16);
      ss += __shfl_xor(ss, 32);
      if (lq == 0) {
        if (c < 512) atomicAdd(&qsum[b * 512 + c], ss);
        else atomicAdd(&ksum[b * 512 + c - 512], ss);
      }
    }
    __syncthreads();
    const int jj = tid & 15, mrow = tid >> 4;
#pragma unroll
    for (int p = 0; p < 8; p++) {
      int m_l = p * 16 + mrow;
      ushort8 v8 = *(const ushort8*)&T[m_l * 128 + ((jj ^ (m_l & 15)) << 3)];
      *(ushort8*)&out[(size_t)(bm + m_l) * N + bn + jj * 8] = v8;
    }
  } else {
#pragma unroll
    for (int j = 0; j < 4; j++) {
      int c = bn + wn + j * 16 + l15;
      int hd = c - 1024;
      ushort* vrow = vt + ((size_t)(b * 512 + hd)) * HW_;
#pragma unroll
      for (int i = 0; i < 4; i++) {
        int n0 = (bm & 1023) + wm + i * 16 + lq * 4;
        union { unsigned u[2]; ushort4_t s; } pu;
        pu.u[0] = cvt_pk_bf16(acc[i][j][0], acc[i][j][1]);
        pu.u[1] = cvt_pk_bf16(acc[i][j][2], acc[i][j][3]);
        *(ushort4_t*)&vrow[n0] = pu.s;
      }
    }
  }
}

// -------------------------------------------------------------------------
// bf16 MFMA GEMM 128x64 tiles, BK=64 (8 K-steps), single-buffered.
// XCD-locality remap. EPI 2 (pointwise conv): f32 +bias +resid(bf16),
// NCHW store staged via swizzled LDS -> contiguous dwordx4.
template <int EPI>
__global__ __launch_bounds__(256) void gemm_n64(
    const ushort* __restrict__ A, const ushort* __restrict__ Wm,
    const float* __restrict__ bias, void* __restrict__ outv,
    const ushort* __restrict__ resid, int N, int K) {
  __shared__ alignas(16) ushort As[128 * 64];
  __shared__ alignas(16) ushort Bs[64 * 64];
  __shared__ alignas(16) float Cs[EPI == 2 ? 64 * 128 : 4];
  const int f = blockIdx.y * gridDim.x + blockIdx.x;
  const int xcd = f & 7, idx = f >> 3;
  const int nbx = gridDim.x;
  const int bm = (xcd * (gridDim.y >> 3) + idx / nbx) * 128;
  const int bn = (idx % nbx) * 64;
  const int tid = threadIdx.x;
  const int w = tid >> 6, lane = tid & 63;
  const int wm = 64 * (w & 1), wn = 32 * (w >> 1);
  const int l15 = lane & 15, lq = lane >> 4;

  f32x4 acc[4][2];
#pragma unroll
  for (int i = 0; i < 4; i++)
#pragma unroll
    for (int j = 0; j < 2; j++) acc[i][j] = (f32x4){0.f, 0.f, 0.f, 0.f};

  const int srr8 = lane >> 3, sq3 = lane & 7;

  for (int k0 = 0; k0 < K; k0 += 64) {
    __syncthreads();
#pragma unroll
    for (int it = 0; it < 4; it++) {
      int r = w * 32 + it * 8 + srr8;
      int g = (sq3 - r) & 7;
      GLD16(A + (size_t)(bm + r) * K + k0 + g * 8, &As[(w * 32 + it * 8) * 64]);
    }
#pragma unroll
    for (int it = 0; it < 2; it++) {
      int r = w * 16 + it * 8 + srr8;
      int g = (sq3 - r) & 7;
      GLD16(Wm + (size_t)(bn + r) * K + k0 + g * 8, &Bs[(w * 16 + it * 8) * 64]);
    }
    __syncthreads();
#pragma unroll
    for (int kk = 0; kk < 2; kk++) {
      short8 af[4], bf[2];
#pragma unroll
      for (int nt = 0; nt < 4; nt++) {
        int r = wm + nt * 16 + l15;
        af[nt] = *(const short8*)&As[r * 64 + (((kk * 4 + lq) + r) & 7) * 8];
      }
#pragma unroll
      for (int j = 0; j < 2; j++) {
        int c = wn + j * 16 + l15;
        bf[j] = *(const short8*)&Bs[c * 64 + (((kk * 4 + lq) + c) & 7) * 8];
      }
#pragma unroll
      for (int i = 0; i < 4; i++)
#pragma unroll
        for (int j = 0; j < 2; j++)
          acc[i][j] = __builtin_amdgcn_mfma_f32_16x16x32_bf16(
              af[i], bf[j], acc[i][j], 0, 0, 0);
    }
  }

  if (EPI == 1) {
#pragma unroll
    for (int i = 0; i < 4; i++) {
#pragma unroll
      for (int j = 0; j < 2; j++) {
        int c = bn + wn + j * 16 + l15;
        float bv = bias[c];
#pragma unroll
        for (int r = 0; r < 4; r++) {
          int m = bm + wm + i * 16 + lq * 4 + r;
          float v = acc[i][j][r] + bv;
          ((ushort*)outv)[(size_t)m * N + c] = f2bf(v);
        }
      }
    }
  } else {
    // Phase 1: acc(+bias+resid) -> Cs[c][m], float4 chunks XOR-swizzled.
#pragma unroll
    for (int i = 0; i < 4; i++) {
#pragma unroll
      for (int j = 0; j < 2; j++) {
        int c_l = wn + j * 16 + l15;
        int m_l = wm + i * 16 + lq * 4;
        float bv = bias[bn + c_l];
        f32x4 vv;
#pragma unroll
        for (int r = 0; r < 4; r++) {
          int m = bm + m_l + r;
          vv[r] = acc[i][j][r] + bv + bf2f(resid[(size_t)m * C_ + bn + c_l]);
        }
        int phys = (m_l >> 2) ^ (c_l & 31);
        *(f32x4*)&Cs[c_l * 128 + phys * 4] = vv;
      }
    }
    __syncthreads();
    // Phase 2: per c-row contiguous 512B stores (dwordx4, 32 lanes/row).
    const int b = bm >> 10, s0 = bm & (HW_ - 1);
    const int l5 = tid & 31;
    const int rr = tid >> 5;  // 0..7
    float* outp = (float*)outv;
#pragma unroll
    for (int pass = 0; pass < 8; pass++) {
      int row = rr + pass * 8;  // local c in [0,64)
      int phys = l5 ^ (row & 31);
      f32x4 vv = *(const f32x4*)&Cs[row * 128 + phys * 4];
      *(f32x4*)&outp[((size_t)(b * C_ + bn + row)) * HW_ + s0 + l5 * 4] = vv;
    }
  }
}

// -------------------------------------------------------------------------
// K3: MFMA flash attention, 32 queries/wave (128q/block, grid 512),
// bh-minor XCD-local order. K=32 PV via fragment concatenation.
__global__ __launch_bounds__(256) void attn_mfma_kernel(
    const ushort* __restrict__ qkv, const ushort* __restrict__ vt,
    const float* __restrict__ qsum, const float* __restrict__ ksum,
    const float* __restrict__ temp, ushort* __restrict__ o) {
  __shared__ alignas(16) ushort Ks[2][64 * 64];   // [key][d], chunk-swizzled
  __shared__ alignas(16) ushort Vts[2][64 * 64];  // [d][key], chunk-swizzled
  __shared__ float sc_lds[64];

  const int tid = threadIdx.x;
  const int w = tid >> 6, lane = tid & 63;
  const int quad = lane >> 4, lcol = lane & 15;
  const int bh = blockIdx.x & 63;   // XCD-locality: bh determines XCD
  const int qt = blockIdx.x >> 6;   // 0..7
  const int b = bh >> 3, h = bh & 7;
  const int q0 = qt * 128;

  if (tid < 64) {
    float qs = qsum[b * 512 + h * 64 + tid];
    float ks = ksum[b * 512 + h * 64 + tid];
    float iq = 1.0f / fmaxf(sqrtf(qs), 1e-12f);
    float ik = 1.0f / fmaxf(sqrtf(ks), 1e-12f);
    sc_lds[tid] = iq * ik * temp[h] * 1.44269504088896340736f;  // fold log2e
  }

  const ushort* kg = qkv + (size_t)b * HW_ * C3_ + C_ + h * 64;
  const ushort* vg = vt + (size_t)(bh * 64) * HW_;

  // staging: 256 threads x 2 iters cover 64 rows x 8 chunks (of 8 bf16)
  const int srow0 = tid >> 3;  // 0..31
  const int sc = tid & 7;

  // prologue: stage tile 0 into buffer 0
#pragma unroll
  for (int it = 0; it < 2; it++) {
    int row = srow0 + it * 32;
    int scg = sc ^ (row & 7);
    GLD16(kg + (size_t)row * C3_ + scg * 8, &Ks[0][w * 512 + it * 2048]);
    GLD16(vg + (size_t)row * HW_ + scg * 8, &Vts[0][w * 512 + it * 2048]);
  }
  __syncthreads();

  // Q fragments for both q-groups (B-operand of S^T = K·Q^T), scales folded.
  short8 qf[2][2];
#pragma unroll
  for (int qg = 0; qg < 2; qg++) {
    const int m = q0 + w * 32 + qg * 16 + lcol;
    const ushort* qrow = qkv + ((size_t)(b * HW_ + m)) * C3_ + h * 64;
#pragma unroll
    for (int kc = 0; kc < 2; kc++) {
      ushort8 q8 = *(const ushort8*)&qrow[kc * 32 + quad * 8];
      union { short8 v; ushort u[8]; } pk;
#pragma unroll
      for (int j = 0; j < 8; j++) {
        int d = kc * 32 + quad * 8 + j;
        pk.u[j] = f2bf(bf2f(q8[j]) * sc_lds[d]);
      }
      qf[qg][kc] = pk.v;
    }
  }

  f32x4 ot[2][4];
#pragma unroll
  for (int qg = 0; qg < 2; qg++)
#pragma unroll
    for (int dt = 0; dt < 4; dt++) ot[qg][dt] = (f32x4){0.f, 0.f, 0.f, 0.f};
  float lsum[2] = {0.f, 0.f};

  for (int kt = 0; kt < 16; kt++) {
    if (kt > 0) __syncthreads();  // drains GLD(kt) + prior buffer reads
    const int cur = kt & 1;
    if (kt + 1 < 16) {
      const int nxt = cur ^ 1;
#pragma unroll
      for (int it = 0; it < 2; it++) {
        int row = srow0 + it * 32;
        int scg = sc ^ (row & 7);
        GLD16(kg + (size_t)((kt + 1) * 64 + row) * C3_ + scg * 8,
              &Ks[nxt][w * 512 + it * 2048]);
        GLD16(vg + (size_t)row * HW_ + (kt + 1) * 64 + scg * 8,
              &Vts[nxt][w * 512 + it * 2048]);
      }
    }

    // S^T = K·Q^T for both q-groups; each K fragment read used twice
    f32x4 sfr[2][4];
#pragma unroll
    for (int qg = 0; qg < 2; qg++)
#pragma unroll
      for (int nt = 0; nt < 4; nt++) sfr[qg][nt] = (f32x4){0.f, 0.f, 0.f, 0.f};
#pragma unroll
    for (int kc = 0; kc < 2; kc++) {
#pragma unroll
      for (int nt = 0; nt < 4; nt++) {
        int row = nt * 16 + lcol;
        short8 kf = *(const short8*)
            &Ks[cur][row * 64 + (((kc * 4 + quad) ^ (row & 7)) * 8)];
        sfr[0][nt] = __builtin_amdgcn_mfma_f32_16x16x32_bf16(kf, qf[0][kc],
                                                             sfr[0][nt], 0, 0, 0);
        sfr[1][nt] = __builtin_amdgcn_mfma_f32_16x16x32_bf16(kf, qf[1][kc],
                                                             sfr[1][nt], 0, 0, 0);
      }
    }

    // exp2 + per-lane sum + pack P pairs via cvt_pk
    unsigned pu[2][4][2];
#pragma unroll
    for (int qg = 0; qg < 2; qg++) {
#pragma unroll
      for (int nt = 0; nt < 4; nt++) {
        float f0 = fast_exp2(sfr[qg][nt][0]);
        float f1 = fast_exp2(sfr[qg][nt][1]);
        float f2 = fast_exp2(sfr[qg][nt][2]);
        float f3 = fast_exp2(sfr[qg][nt][3]);
        lsum[qg] += f0 + f1 + f2 + f3;
        pu[qg][nt][0] = cvt_pk_bf16(f0, f1);
        pu[qg][nt][1] = cvt_pk_bf16(f2, f3);
      }
    }

    // O^T += V^T · P^T with K=32 MFMA (fragment concat, register-local).
#pragma unroll
    for (int ntp = 0; ntp < 2; ntp++) {
      union { unsigned u[4]; short8 v; } pf0, pf1;
      pf0.u[0] = pu[0][2 * ntp][0];
      pf0.u[1] = pu[0][2 * ntp][1];
      pf0.u[2] = pu[0][2 * ntp + 1][0];
      pf0.u[3] = pu[0][2 * ntp + 1][1];
      pf1.u[0] = pu[1][2 * ntp][0];
      pf1.u[1] = pu[1][2 * ntp][1];
      pf1.u[2] = pu[1][2 * ntp + 1][0];
      pf1.u[3] = pu[1][2 * ntp + 1][1];
      int key0 = (2 * ntp) * 16 + quad * 4;
      int key1 = (2 * ntp + 1) * 16 + quad * 4;
#pragma unroll
      for (int dt = 0; dt < 4; dt++) {
        int d = dt * 16 + lcol;
        short4v v0 = *(const short4v*)
            &Vts[cur][d * 64 + (((key0 >> 3) ^ (d & 7)) * 8) + (key0 & 7)];
        short4v v1 = *(const short4v*)
            &Vts[cur][d * 64 + (((key1 >> 3) ^ (d & 7)) * 8) + (key1 & 7)];
        short8 vf = {v0[0], v0[1], v0[2], v0[3], v1[0], v1[1], v1[2], v1[3]};
        ot[0][dt] = __builtin_amdgcn_mfma_f32_16x16x32_bf16(vf, pf0.v,
                                                            ot[0][dt], 0, 0, 0);
        ot[1][dt] = __builtin_amdgcn_mfma_f32_16x16x32_bf16(vf, pf1.v,
                                                            ot[1][dt], 0, 0, 0);
      }
    }
  }

#pragma unroll
  for (int qg = 0; qg < 2; qg++) {
    float s = lsum[qg];
    s += __shfl_xor(s, 16);
    s += __shfl_xor(s, 32);
    const float inv = 1.0f / s;
    const int m = q0 + w * 32 + qg * 16 + lcol;
    ushort* orow = o + ((size_t)(b * HW_ + m)) * C_ + h * 64;
#pragma unroll
    for (int dt = 0; dt < 4; dt++) {
      union { unsigned u[2]; ushort4_t s4; } pu2;
      pu2.u[0] = cvt_pk_bf16(ot[qg][dt][0] * inv, ot[qg][dt][1] * inv);
      pu2.u[1] = cvt_pk_bf16(ot[qg][dt][2] * inv, ot[qg][dt][3] * inv);
      *(ushort4_t*)&orow[dt * 16 + quad * 4] = pu2.s4;
    }
  }
}

// -------------------------------------------------------------------------
// K4 (fused): proj GEMM + bias + LayerNorm + residual(xT) -> y_bf.
// 16 tokens x 512 ch per block, grid 512 -> 2 blocks/CU.
// Epilogue: phase 1 stages exact-f32 LN output in swizzled LDS (reusing
// Bs); phase 2 adds resid (coalesced ushort8 reads) and stores ushort8
// (was: 16 scalar 2B loads + 16 scalar 2B stores per lane).
__global__ __launch_bounds__(512) void gemm_proj_ln(
    const ushort* __restrict__ A, const ushort* __restrict__ Wm,
    const float* __restrict__ bias, const float* __restrict__ g,
    const float* __restrict__ bb, const ushort* __restrict__ resid,
    ushort* __restrict__ ybf) {
  __shared__ alignas(16) ushort As[2][16 * 32];
  __shared__ alignas(16) ushort Bs[2][512 * 32];
  __shared__ float red[8][16][2];
  const int bm = blockIdx.x * 16;
  const int tid = threadIdx.x;
  const int w = tid >> 6, lane = tid & 63;
  const int l15 = lane & 15, lq = lane >> 4;
  const int srr = lane >> 2, sq1 = lane & 3;

  f32x4 acc[4];
#pragma unroll
  for (int j = 0; j < 4; j++) acc[j] = (f32x4){0.f, 0.f, 0.f, 0.f};

  auto stage = [&](int kt, int bufi) {
#pragma unroll
    for (int it = 0; it < 4; it++) {
      int r = it * 128 + w * 16 + srr;
      int q = (sq1 - (r >> 1)) & 3;
      GLD16(Wm + (size_t)r * C_ + kt * 32 + q * 8,
            &Bs[bufi][(it * 128 + w * 16) * 32]);
    }
    if (w == 0) {
      int r = srr;  // 0..15
      int q = (sq1 - (r >> 1)) & 3;
      GLD16(A + (size_t)(bm + r) * C_ + kt * 32 + q * 8, &As[bufi][0]);
    }
  };

  stage(0, 0);

  for (int ks = 0; ks < 16; ks++) {
    __syncthreads();
    const int cur = ks & 1;
    if (ks + 1 < 16) stage(ks + 1, cur ^ 1);

    short8 af, bf[4];
    {
      int r = l15;
      af = *(const short8*)&As[cur][r * 32 + (((lq + (r >> 1)) & 3) * 8)];
    }
#pragma unroll
    for (int j = 0; j < 4; j++) {
      int c = w * 64 + j * 16 + l15;
      bf[j] = *(const short8*)&Bs[cur][c * 32 + (((lq + (c >> 1)) & 3) * 8)];
    }
#pragma unroll
    for (int j = 0; j < 4; j++)
      acc[j] = __builtin_amdgcn_mfma_f32_16x16x32_bf16(af, bf[j], acc[j],
                                                       0, 0, 0);
  }

  float bv[4];
#pragma unroll
  for (int j = 0; j < 4; j++) bv[j] = bias[w * 64 + j * 16 + l15];

  float s1v[4], s2v[4];
#pragma unroll
  for (int r = 0; r < 4; r++) {
    float a = 0.f, q2 = 0.f;
#pragma unroll
    for (int j = 0; j < 4; j++) {
      float v = acc[j][r] + bv[j];
      acc[j][r] = v;
      a += v;
      q2 += v * v;
    }
    s1v[r] = a;
    s2v[r] = q2;
  }
#pragma unroll
  for (int off = 1; off < 16; off <<= 1) {
#pragma unroll
    for (int r = 0; r < 4; r++) {
      s1v[r] += __shfl_xor(s1v[r], off);
      s2v[r] += __shfl_xor(s2v[r], off);
    }
  }
  if (l15 == 0) {
#pragma unroll
    for (int r = 0; r < 4; r++) {
      int tok = lq * 4 + r;
      red[w][tok][0] = s1v[r];
      red[w][tok][1] = s2v[r];
    }
  }
  __syncthreads();  // also: all Bs reads done -> T may reuse Bs

  float gv[4], bbv[4];
#pragma unroll
  for (int j = 0; j < 4; j++) {
    gv[j] = g[w * 64 + j * 16 + l15];
    bbv[j] = bb[w * 64 + j * 16 + l15];
  }

  // phase 1: LN result (pre-residual, exact f32) -> T, chunk-swizzled
  float* T = (float*)&Bs[0][0];  // 16 tok x 512 ch f32 = 32 KB
#pragma unroll
  for (int r = 0; r < 4; r++) {
    int tok = lq * 4 + r;
    float su = 0.f, sq = 0.f;
#pragma unroll
    for (int ww = 0; ww < 8; ww++) {
      su += red[ww][tok][0];
      sq += red[ww][tok][1];
    }
    float mu = su * (1.0f / C_);
    float var = sq * (1.0f / C_) - mu * mu;
    float rstd = rsqrtf(var + 1e-5f);
    int s = (tok << 3) | (tok & 7);
#pragma unroll
    for (int j = 0; j < 4; j++) {
      int c = w * 64 + j * 16 + l15;
      float y = (acc[j][r] - mu) * rstd * gv[j] + bbv[j];
      int q = c >> 2;
      T[tok * 512 + (((q ^ s) & 127) << 2) + (c & 3)] = y;
    }
  }
  __syncthreads();

  // phase 2: +resid (ushort8), pack, contiguous ushort8 stores.
  const int mrow = tid >> 5, j0 = tid & 31;
  const int s2 = (mrow << 3) | (mrow & 7);
#pragma unroll
  for (int p = 0; p < 2; p++) {
    int c0 = p * 256 + j0 * 8;
    int q0 = c0 >> 2;
    f32x4 a = *(const f32x4*)&T[mrow * 512 + (((q0 ^ s2) & 127) << 2)];
    f32x4 b2 = *(const f32x4*)&T[mrow * 512 + ((((q0 + 1) ^ s2) & 127) << 2)];
    int m = bm + mrow;
    ushort8 r8 = *(const ushort8*)&resid[(size_t)m * C_ + c0];
    union { unsigned u[4]; ushort8 v; } pk;
    pk.u[0] = cvt_pk_bf16(a[0] + bf2f(r8[0]), a[1] + bf2f(r8[1]));
    pk.u[1] = cvt_pk_bf16(a[2] + bf2f(r8[2]), a[3] + bf2f(r8[3]));
    pk.u[2] = cvt_pk_bf16(b2[0] + bf2f(r8[4]), b2[1] + bf2f(r8[5]));
    pk.u[3] = cvt_pk_bf16(b2[2] + bf2f(r8[6]), b2[3] + bf2f(r8[7]));
    *(ushort8*)&ybf[(size_t)m * C_ + c0] = pk.v;
  }
}

// -------------------------------------------------------------------------
// K6: depthwise 3x3 SAME on bf16 y (token-major) -> bf16 out (+dw bias)
__global__ __launch_bounds__(256) void dwconv_kernel(
    const ushort* __restrict__ y, const float* __restrict__ w,
    const float* __restrict__ bias, ushort* __restrict__ out) {
  const int cg = threadIdx.x & 63, tg = threadIdx.x >> 6;
  const int c0 = cg * 8;
  float wreg[9][8], breg[8];
#pragma unroll
  for (int j = 0; j < 8; j++) {
    breg[j] = bias[c0 + j];
#pragma unroll
    for (int kk = 0; kk < 9; kk++) wreg[kk][j] = w[(c0 + j) * 9 + kk];
  }
  for (int i = 0; i < 4; i++) {
    int token = blockIdx.x * 16 + tg * 4 + i;
    int b = token >> 10, s = token & (HW_ - 1);
    int hh = s >> 5, ww = s & 31;
    float acc[8];
#pragma unroll
    for (int j = 0; j < 8; j++) acc[j] = breg[j];
#pragma unroll
    for (int ky = 0; ky < 3; ky++) {
      int yy = hh + ky - 1;
      if (yy < 0 || yy >= HH_) continue;
#pragma unroll
      for (int kx = 0; kx < 3; kx++) {
        int xx = ww + kx - 1;
        if (xx < 0 || xx >= WW_) continue;
        ushort8 v8 = *(const ushort8*)
            &y[((size_t)(b * HW_ + yy * 32 + xx)) * C_ + c0];
        const float* wk = wreg[ky * 3 + kx];
#pragma unroll
        for (int j = 0; j < 8; j++) acc[j] += wk[j] * bf2f(v8[j]);
      }
    }
    union { unsigned u[4]; ushort8 v; } pku;
    pku.u[0] = cvt_pk_bf16(acc[0], acc[1]);
    pku.u[1] = cvt_pk_bf16(acc[2], acc[3]);
    pku.u[2] = cvt_pk_bf16(acc[4], acc[5]);
    pku.u[3] = cvt_pk_bf16(acc[6], acc[7]);
    *(ushort8*)&out[(size_t)token * C_ + c0] = pku.v;
  }
}

// -------------------------------------------------------------------------
extern "C" void kernel_launch(void* const* d_in, const int* in_sizes, int n_in,
                              void* d_out, int out_size, void* d_ws,
                              size_t ws_size, hipStream_t stream) {
  const float* x = (const float*)d_in[0];
  const float* qkv_w = (const float*)d_in[1];
  const float* proj_w = (const float*)d_in[2];
  const float* proj_b = (const float*)d_in[3];
  const float* temperature = (const float*)d_in[4];
  const float* ln_g = (const float*)d_in[5];
  const float* ln_b = (const float*)d_in[6];
  const float* pos = (const float*)d_in[7];
  const float* dw_w = (const float*)d_in[8];
  const float* dw_b = (const float*)d_in[9];
  const float* pw_w = (const float*)d_in[10];
  const float* pw_b = (const float*)d_in[11];
  float* out = (float*)d_out;

  float* ws = (float*)d_ws;
  ushort* qkv_bf = (ushort*)ws;
  ushort* t_bf = (ushort*)(ws + (size_t)6 * 1024 * 1024);
  ushort* xT_bf = (ushort*)(ws + (size_t)12 * 1024 * 1024);
  ushort* wts = (ushort*)(ws + (size_t)14 * 1024 * 1024);
  ushort* qkvw_bf = wts;
  ushort* projw_bf = wts + 786432;
  ushort* pww_bf = wts + 1048576;
  float* sums = ws + (size_t)15 * 1024 * 1024;
  float* qsum = sums;
  float* ksum = sums + 4096;
  ushort* vtb = (ushort*)(ws + (size_t)16 * 1024 * 1024);

  const int M = BB_ * HW_;  // 8192 tokens

  // 1) prep: weights->bf16 (x4 vec), t/xT transpose, zero sums
  prep_kernel<<<2336, 256, 0, stream>>>(x, pos, qkv_w, proj_w, pw_w, t_bf,
                                        xT_bf, wts, sums);
  // 2) qkv GEMM (BK=64, XCD-local bm, LDS-staged q/k stores)
  gemm_qkv<<<dim3(C3_ / 128, M / 128), 256, 0, stream>>>(
      t_bf, qkvw_bf, qkv_bf, vtb, qsum, ksum);
  // 3) flash attention (128q/block, K=32 PV via fragment concat) -> attn_out
  attn_mfma_kernel<<<BB_ * NH_ * (HW_ / 128), 256, 0, stream>>>(
      qkv_bf, vtb, qsum, ksum, temperature, t_bf);
  // 4+5) fused proj GEMM + bias + LayerNorm + residual -> y_bf (over xT)
  gemm_proj_ln<<<M / 16, 512, 0, stream>>>(t_bf, projw_bf, proj_b, ln_g,
                                           ln_b, xT_bf, xT_bf);
  // 6) depthwise 3x3 on bf16 y -> dw_out (bf16, reuses t region)
  dwconv_kernel<<<M / 16, 256, 0, stream>>>(xT_bf, dw_w, dw_b, t_bf);
  // 7) pointwise GEMM (BK=64, XCD-local bm) + pw_b + residual, NCHW -> out
  gemm_n64<2><<<dim3(C_ / 64, M / 128), 256, 0, stream>>>(
      t_bf, pww_bf, pw_b, out, xT_bf, C_, C_);
}

// Round 9
// 187.492 us; speedup vs baseline: 1.0494x; 1.0171x over previous
//
#include <hip/hip_runtime.h>
#include <math.h>

// Problem constants
#define BB_ 8
#define C_ 512
#define C3_ 1536
#define HW_ 1024
#define NH_ 8
#define DH_ 64
#define HH_ 32
#define WW_ 32

typedef __attribute__((ext_vector_type(8))) short short8;
typedef __attribute__((ext_vector_type(4))) short short4v;
typedef __attribute__((ext_vector_type(8))) unsigned short ushort8;
typedef __attribute__((ext_vector_type(4))) unsigned short ushort4_t;
typedef __attribute__((ext_vector_type(4))) float f32x4;
typedef unsigned short ushort;

__device__ inline ushort f2bf(float f) {
  union { float f; unsigned u; } v;
  v.f = f;
  unsigned r = v.u + 0x7fffu + ((v.u >> 16) & 1u);
  return (ushort)(r >> 16);
}
__device__ inline float bf2f(ushort u) {
  union { unsigned u; float f; } v;
  v.u = ((unsigned)u) << 16;
  return v.f;
}

// One-instruction RNE pack of two f32 -> two bf16 (lo=a, hi=b).
__device__ inline unsigned cvt_pk_bf16(float a, float b) {
  unsigned r;
  asm("v_cvt_pk_bf16_f32 %0, %1, %2" : "=v"(r) : "v"(a), "v"(b));
  return r;
}

__device__ inline float fast_exp2(float x) {
#if __has_builtin(__builtin_amdgcn_exp2f)
  return __builtin_amdgcn_exp2f(x);
#else
  return exp2f(x);
#endif
}

#define GLD16(gptr, lptr)                                                     \
  __builtin_amdgcn_global_load_lds(                                           \
      (const __attribute__((address_space(1))) unsigned int*)(gptr),          \
      (__attribute__((address_space(3))) unsigned int*)(lptr), 16, 0, 0)

// -------------------------------------------------------------------------
// K1 (prep): fused weight-cvt (x4 vectorized) + x transpose(+pos) +
// qsum/ksum zeroing. Grid: 1024 transpose + 1280 wcvt + 32 sums = 2336.
__global__ __launch_bounds__(256) void prep_kernel(
    const float* __restrict__ x, const float* __restrict__ pos,
    const float* __restrict__ qkv_w, const float* __restrict__ proj_w,
    const float* __restrict__ pw_w, ushort* __restrict__ t,
    ushort* __restrict__ xT, ushort* __restrict__ wts,
    float* __restrict__ sums) {
  const int bid = blockIdx.x;
  const int tid = threadIdx.x;
  if (bid >= 2304) {
    sums[(bid - 2304) * 256 + tid] = 0.f;
    return;
  }
  if (bid >= 1024) {
    int i = ((bid - 1024) * 256 + tid) * 4;
    float4 v;
    if (i < 786432) v = *(const float4*)&qkv_w[i];
    else if (i < 1048576) v = *(const float4*)&proj_w[i - 786432];
    else v = *(const float4*)&pw_w[i - 1048576];
    union { unsigned u[2]; ushort4_t s; } o4;
    o4.u[0] = cvt_pk_bf16(v.x, v.y);
    o4.u[1] = cvt_pk_bf16(v.z, v.w);
    *(ushort4_t*)&wts[i] = o4.s;
    return;
  }
  __shared__ float tile[64][65];
  const int n0 = (bid & 15) * 64, c0 = ((bid >> 4) & 7) * 64, b = bid >> 7;
#pragma unroll
  for (int it = 0; it < 4; it++) {
    int c_l = (tid >> 4) + it * 16;
    int n_l4 = (tid & 15) * 4;
    float4 v = *(const float4*)&x[((size_t)(b * C_ + c0 + c_l)) * HW_ + n0 + n_l4];
    tile[c_l][n_l4 + 0] = v.x;
    tile[c_l][n_l4 + 1] = v.y;
    tile[c_l][n_l4 + 2] = v.z;
    tile[c_l][n_l4 + 3] = v.w;
  }
  __syncthreads();
#pragma unroll
  for (int it = 0; it < 4; it++) {
    int n_l = (tid >> 4) + it * 16;
    int c_l4 = (tid & 15) * 4;
    size_t token = (size_t)(b * HW_ + n0 + n_l);
    float4 pv = *(const float4*)&pos[(n0 + n_l) * C_ + c0 + c_l4];
    float xv0 = tile[c_l4 + 0][n_l], xv1 = tile[c_l4 + 1][n_l];
    float xv2 = tile[c_l4 + 2][n_l], xv3 = tile[c_l4 + 3][n_l];
    ushort4_t tb = {f2bf(xv0 + pv.x), f2bf(xv1 + pv.y), f2bf(xv2 + pv.z),
                    f2bf(xv3 + pv.w)};
    ushort4_t xb = {f2bf(xv0), f2bf(xv1), f2bf(xv2), f2bf(xv3)};
    *(ushort4_t*)&t[token * C_ + c0 + c_l4] = tb;
    *(ushort4_t*)&xT[token * C_ + c0 + c_l4] = xb;
  }
}

// -------------------------------------------------------------------------
// K2: qkv GEMM, BK=64 (8 K-steps). Row-swizzled 8-chunk LDS. XCD-local bm.
// Both epilogues stage through LDS (reusing As+Bs) for contiguous ushort8
// global stores: q/k 128m x 128c tile; V 128c x 128n transposed tile
// (was: 16 scattered 8B stores/lane for V).
__global__ __launch_bounds__(256) void gemm_qkv(
    const ushort* __restrict__ A, const ushort* __restrict__ Wm,
    ushort* __restrict__ out, ushort* __restrict__ vt,
    float* __restrict__ qsum, float* __restrict__ ksum) {
  const int N = C3_, K = C_;
  __shared__ alignas(16) ushort smem[2 * 128 * 64];
  ushort* As = smem;
  ushort* Bs = smem + 128 * 64;
  const int f = blockIdx.y * gridDim.x + blockIdx.x;  // 0..767
  const int xcd = f & 7, idx = f >> 3;                // idx 0..95
  const int bm = (xcd * 8 + idx / 12) * 128;
  const int bn = (idx % 12) * 128;
  const int tid = threadIdx.x;
  const int w = tid >> 6, lane = tid & 63;
  const int wm = 64 * (w & 1), wn = 64 * (w >> 1);
  const int l15 = lane & 15, lq = lane >> 4;

  f32x4 acc[4][4];
#pragma unroll
  for (int i = 0; i < 4; i++)
#pragma unroll
    for (int j = 0; j < 4; j++) acc[i][j] = (f32x4){0.f, 0.f, 0.f, 0.f};

  const int srr8 = lane >> 3, sq3 = lane & 7;

  for (int k0 = 0; k0 < K; k0 += 64) {
    __syncthreads();
#pragma unroll
    for (int it = 0; it < 4; it++) {
      int r = w * 32 + it * 8 + srr8;
      int g = (sq3 - r) & 7;
      GLD16(A + (size_t)(bm + r) * K + k0 + g * 8, &As[(w * 32 + it * 8) * 64]);
      GLD16(Wm + (size_t)(bn + r) * K + k0 + g * 8, &Bs[(w * 32 + it * 8) * 64]);
    }
    __syncthreads();
#pragma unroll
    for (int kk = 0; kk < 2; kk++) {
      short8 af[4], bf[4];
#pragma unroll
      for (int nt = 0; nt < 4; nt++) {
        int r = wm + nt * 16 + l15;
        af[nt] = *(const short8*)&As[r * 64 + (((kk * 4 + lq) + r) & 7) * 8];
        int c = wn + nt * 16 + l15;
        bf[nt] = *(const short8*)&Bs[c * 64 + (((kk * 4 + lq) + c) & 7) * 8];
      }
#pragma unroll
      for (int i = 0; i < 4; i++)
#pragma unroll
        for (int j = 0; j < 4; j++)
          acc[i][j] = __builtin_amdgcn_mfma_f32_16x16x32_bf16(
              af[i], bf[j], acc[i][j], 0, 0, 0);
    }
  }

  const int b = bm >> 10;
  if (bn < 1024) {
    __syncthreads();  // all LDS reads of As/Bs done before T reuse
    ushort* T = smem;  // 128m x 128c bf16, chunk-swizzled
#pragma unroll
    for (int j = 0; j < 4; j++) {
      int c_l = wn + j * 16 + l15;
      int c = bn + c_l;
      float ss = 0.f;
#pragma unroll
      for (int i = 0; i < 4; i++) {
#pragma unroll
        for (int r = 0; r < 4; r++) {
          int m_l = wm + i * 16 + lq * 4 + r;
          float v = acc[i][j][r];
          ss += v * v;
          T[m_l * 128 + (((c_l >> 3) ^ (m_l & 15)) << 3) + (c_l & 7)] =
              f2bf(v);
        }
      }
      ss += __shfl_xor(ss, 16);
      ss += __shfl_xor(ss, 32);
      if (lq == 0) {
        if (c < 512) atomicAdd(&qsum[b * 512 + c], ss);
        else atomicAdd(&ksum[b * 512 + c - 512], ss);
      }
    }
    __syncthreads();
    const int jj = tid & 15, mrow = tid >> 4;
#pragma unroll
    for (int p = 0; p < 8; p++) {
      int m_l = p * 16 + mrow;
      ushort8 v8 = *(const ushort8*)&T[m_l * 128 + ((jj ^ (m_l & 15)) << 3)];
      *(ushort8*)&out[(size_t)(bm + m_l) * N + bn + jj * 8] = v8;
    }
  } else {
    // V: stage 128c x 128n transposed tile in LDS -> contiguous stores.
    __syncthreads();  // all LDS reads of As/Bs done before T reuse
    ushort* T = smem;  // 128c x 128n bf16, chunk-swizzled on n
#pragma unroll
    for (int j = 0; j < 4; j++) {
      int c_l = wn + j * 16 + l15;  // local d-channel row
#pragma unroll
      for (int i = 0; i < 4; i++) {
        int n_l = wm + i * 16 + lq * 4;  // local token, 4 consecutive
        union { unsigned u[2]; ushort4_t s; } pu;
        pu.u[0] = cvt_pk_bf16(acc[i][j][0], acc[i][j][1]);
        pu.u[1] = cvt_pk_bf16(acc[i][j][2], acc[i][j][3]);
        *(ushort4_t*)&T[c_l * 128 + (((n_l >> 3) ^ (c_l & 15)) << 3) +
                        (n_l & 7)] = pu.s;
      }
    }
    __syncthreads();
    const int jj = tid & 15, crow = tid >> 4;
    const int n0 = bm & 1023;
#pragma unroll
    for (int p = 0; p < 8; p++) {
      int c_l = p * 16 + crow;
      ushort8 v8 = *(const ushort8*)&T[c_l * 128 + ((jj ^ (c_l & 15)) << 3)];
      int hd = bn - 1024 + c_l;
      *(ushort8*)&vt[((size_t)(b * 512 + hd)) * HW_ + n0 + jj * 8] = v8;
    }
  }
}

// -------------------------------------------------------------------------
// bf16 MFMA GEMM 128x64 tiles, BK=64 (8 K-steps), single-buffered.
// XCD-locality remap. EPI 2 (pointwise conv): f32 +bias +resid(bf16),
// NCHW store staged via swizzled LDS -> contiguous dwordx4.
template <int EPI>
__global__ __launch_bounds__(256) void gemm_n64(
    const ushort* __restrict__ A, const ushort* __restrict__ Wm,
    const float* __restrict__ bias, void* __restrict__ outv,
    const ushort* __restrict__ resid, int N, int K) {
  __shared__ alignas(16) ushort As[128 * 64];
  __shared__ alignas(16) ushort Bs[64 * 64];
  __shared__ alignas(16) float Cs[EPI == 2 ? 64 * 128 : 4];
  const int f = blockIdx.y * gridDim.x + blockIdx.x;
  const int xcd = f & 7, idx = f >> 3;
  const int nbx = gridDim.x;
  const int bm = (xcd * (gridDim.y >> 3) + idx / nbx) * 128;
  const int bn = (idx % nbx) * 64;
  const int tid = threadIdx.x;
  const int w = tid >> 6, lane = tid & 63;
  const int wm = 64 * (w & 1), wn = 32 * (w >> 1);
  const int l15 = lane & 15, lq = lane >> 4;

  f32x4 acc[4][2];
#pragma unroll
  for (int i = 0; i < 4; i++)
#pragma unroll
    for (int j = 0; j < 2; j++) acc[i][j] = (f32x4){0.f, 0.f, 0.f, 0.f};

  const int srr8 = lane >> 3, sq3 = lane & 7;

  for (int k0 = 0; k0 < K; k0 += 64) {
    __syncthreads();
#pragma unroll
    for (int it = 0; it < 4; it++) {
      int r = w * 32 + it * 8 + srr8;
      int g = (sq3 - r) & 7;
      GLD16(A + (size_t)(bm + r) * K + k0 + g * 8, &As[(w * 32 + it * 8) * 64]);
    }
#pragma unroll
    for (int it = 0; it < 2; it++) {
      int r = w * 16 + it * 8 + srr8;
      int g = (sq3 - r) & 7;
      GLD16(Wm + (size_t)(bn + r) * K + k0 + g * 8, &Bs[(w * 16 + it * 8) * 64]);
    }
    __syncthreads();
#pragma unroll
    for (int kk = 0; kk < 2; kk++) {
      short8 af[4], bf[2];
#pragma unroll
      for (int nt = 0; nt < 4; nt++) {
        int r = wm + nt * 16 + l15;
        af[nt] = *(const short8*)&As[r * 64 + (((kk * 4 + lq) + r) & 7) * 8];
      }
#pragma unroll
      for (int j = 0; j < 2; j++) {
        int c = wn + j * 16 + l15;
        bf[j] = *(const short8*)&Bs[c * 64 + (((kk * 4 + lq) + c) & 7) * 8];
      }
#pragma unroll
      for (int i = 0; i < 4; i++)
#pragma unroll
        for (int j = 0; j < 2; j++)
          acc[i][j] = __builtin_amdgcn_mfma_f32_16x16x32_bf16(
              af[i], bf[j], acc[i][j], 0, 0, 0);
    }
  }

  if (EPI == 1) {
#pragma unroll
    for (int i = 0; i < 4; i++) {
#pragma unroll
      for (int j = 0; j < 2; j++) {
        int c = bn + wn + j * 16 + l15;
        float bv = bias[c];
#pragma unroll
        for (int r = 0; r < 4; r++) {
          int m = bm + wm + i * 16 + lq * 4 + r;
          float v = acc[i][j][r] + bv;
          ((ushort*)outv)[(size_t)m * N + c] = f2bf(v);
        }
      }
    }
  } else {
    // Phase 1: acc(+bias+resid) -> Cs[c][m], float4 chunks XOR-swizzled.
#pragma unroll
    for (int i = 0; i < 4; i++) {
#pragma unroll
      for (int j = 0; j < 2; j++) {
        int c_l = wn + j * 16 + l15;
        int m_l = wm + i * 16 + lq * 4;
        float bv = bias[bn + c_l];
        f32x4 vv;
#pragma unroll
        for (int r = 0; r < 4; r++) {
          int m = bm + m_l + r;
          vv[r] = acc[i][j][r] + bv + bf2f(resid[(size_t)m * C_ + bn + c_l]);
        }
        int phys = (m_l >> 2) ^ (c_l & 31);
        *(f32x4*)&Cs[c_l * 128 + phys * 4] = vv;
      }
    }
    __syncthreads();
    // Phase 2: per c-row contiguous 512B stores (dwordx4, 32 lanes/row).
    const int b = bm >> 10, s0 = bm & (HW_ - 1);
    const int l5 = tid & 31;
    const int rr = tid >> 5;  // 0..7
    float* outp = (float*)outv;
#pragma unroll
    for (int pass = 0; pass < 8; pass++) {
      int row = rr + pass * 8;  // local c in [0,64)
      int phys = l5 ^ (row & 31);
      f32x4 vv = *(const f32x4*)&Cs[row * 128 + phys * 4];
      *(f32x4*)&outp[((size_t)(b * C_ + bn + row)) * HW_ + s0 + l5 * 4] = vv;
    }
  }
}

// -------------------------------------------------------------------------
// K3: MFMA flash attention, 32 queries/wave (128q/block, grid 512),
// bh-minor XCD-local order. K=32 PV via fragment concatenation.
__global__ __launch_bounds__(256) void attn_mfma_kernel(
    const ushort* __restrict__ qkv, const ushort* __restrict__ vt,
    const float* __restrict__ qsum, const float* __restrict__ ksum,
    const float* __restrict__ temp, ushort* __restrict__ o) {
  __shared__ alignas(16) ushort Ks[2][64 * 64];   // [key][d], chunk-swizzled
  __shared__ alignas(16) ushort Vts[2][64 * 64];  // [d][key], chunk-swizzled
  __shared__ float sc_lds[64];

  const int tid = threadIdx.x;
  const int w = tid >> 6, lane = tid & 63;
  const int quad = lane >> 4, lcol = lane & 15;
  const int bh = blockIdx.x & 63;   // XCD-locality: bh determines XCD
  const int qt = blockIdx.x >> 6;   // 0..7
  const int b = bh >> 3, h = bh & 7;
  const int q0 = qt * 128;

  if (tid < 64) {
    float qs = qsum[b * 512 + h * 64 + tid];
    float ks = ksum[b * 512 + h * 64 + tid];
    float iq = 1.0f / fmaxf(sqrtf(qs), 1e-12f);
    float ik = 1.0f / fmaxf(sqrtf(ks), 1e-12f);
    sc_lds[tid] = iq * ik * temp[h] * 1.44269504088896340736f;  // fold log2e
  }

  const ushort* kg = qkv + (size_t)b * HW_ * C3_ + C_ + h * 64;
  const ushort* vg = vt + (size_t)(bh * 64) * HW_;

  // staging: 256 threads x 2 iters cover 64 rows x 8 chunks (of 8 bf16)
  const int srow0 = tid >> 3;  // 0..31
  const int sc = tid & 7;

  // prologue: stage tile 0 into buffer 0
#pragma unroll
  for (int it = 0; it < 2; it++) {
    int row = srow0 + it * 32;
    int scg = sc ^ (row & 7);
    GLD16(kg + (size_t)row * C3_ + scg * 8, &Ks[0][w * 512 + it * 2048]);
    GLD16(vg + (size_t)row * HW_ + scg * 8, &Vts[0][w * 512 + it * 2048]);
  }
  __syncthreads();

  // Q fragments for both q-groups (B-operand of S^T = K·Q^T), scales folded.
  short8 qf[2][2];
#pragma unroll
  for (int qg = 0; qg < 2; qg++) {
    const int m = q0 + w * 32 + qg * 16 + lcol;
    const ushort* qrow = qkv + ((size_t)(b * HW_ + m)) * C3_ + h * 64;
#pragma unroll
    for (int kc = 0; kc < 2; kc++) {
      ushort8 q8 = *(const ushort8*)&qrow[kc * 32 + quad * 8];
      union { short8 v; ushort u[8]; } pk;
#pragma unroll
      for (int j = 0; j < 8; j++) {
        int d = kc * 32 + quad * 8 + j;
        pk.u[j] = f2bf(bf2f(q8[j]) * sc_lds[d]);
      }
      qf[qg][kc] = pk.v;
    }
  }

  f32x4 ot[2][4];
#pragma unroll
  for (int qg = 0; qg < 2; qg++)
#pragma unroll
    for (int dt = 0; dt < 4; dt++) ot[qg][dt] = (f32x4){0.f, 0.f, 0.f, 0.f};
  float lsum[2] = {0.f, 0.f};

  for (int kt = 0; kt < 16; kt++) {
    if (kt > 0) __syncthreads();  // drains GLD(kt) + prior buffer reads
    const int cur = kt & 1;
    if (kt + 1 < 16) {
      const int nxt = cur ^ 1;
#pragma unroll
      for (int it = 0; it < 2; it++) {
        int row = srow0 + it * 32;
        int scg = sc ^ (row & 7);
        GLD16(kg + (size_t)((kt + 1) * 64 + row) * C3_ + scg * 8,
              &Ks[nxt][w * 512 + it * 2048]);
        GLD16(vg + (size_t)row * HW_ + (kt + 1) * 64 + scg * 8,
              &Vts[nxt][w * 512 + it * 2048]);
      }
    }

    // S^T = K·Q^T for both q-groups; each K fragment read used twice
    f32x4 sfr[2][4];
#pragma unroll
    for (int qg = 0; qg < 2; qg++)
#pragma unroll
      for (int nt = 0; nt < 4; nt++) sfr[qg][nt] = (f32x4){0.f, 0.f, 0.f, 0.f};
#pragma unroll
    for (int kc = 0; kc < 2; kc++) {
#pragma unroll
      for (int nt = 0; nt < 4; nt++) {
        int row = nt * 16 + lcol;
        short8 kf = *(const short8*)
            &Ks[cur][row * 64 + (((kc * 4 + quad) ^ (row & 7)) * 8)];
        sfr[0][nt] = __builtin_amdgcn_mfma_f32_16x16x32_bf16(kf, qf[0][kc],
                                                             sfr[0][nt], 0, 0, 0);
        sfr[1][nt] = __builtin_amdgcn_mfma_f32_16x16x32_bf16(kf, qf[1][kc],
                                                             sfr[1][nt], 0, 0, 0);
      }
    }

    // exp2 + per-lane sum + pack P pairs via cvt_pk
    unsigned pu[2][4][2];
#pragma unroll
    for (int qg = 0; qg < 2; qg++) {
#pragma unroll
      for (int nt = 0; nt < 4; nt++) {
        float f0 = fast_exp2(sfr[qg][nt][0]);
        float f1 = fast_exp2(sfr[qg][nt][1]);
        float f2 = fast_exp2(sfr[qg][nt][2]);
        float f3 = fast_exp2(sfr[qg][nt][3]);
        lsum[qg] += f0 + f1 + f2 + f3;
        pu[qg][nt][0] = cvt_pk_bf16(f0, f1);
        pu[qg][nt][1] = cvt_pk_bf16(f2, f3);
      }
    }

    // O^T += V^T · P^T with K=32 MFMA (fragment concat, register-local).
#pragma unroll
    for (int ntp = 0; ntp < 2; ntp++) {
      union { unsigned u[4]; short8 v; } pf0, pf1;
      pf0.u[0] = pu[0][2 * ntp][0];
      pf0.u[1] = pu[0][2 * ntp][1];
      pf0.u[2] = pu[0][2 * ntp + 1][0];
      pf0.u[3] = pu[0][2 * ntp + 1][1];
      pf1.u[0] = pu[1][2 * ntp][0];
      pf1.u[1] = pu[1][2 * ntp][1];
      pf1.u[2] = pu[1][2 * ntp + 1][0];
      pf1.u[3] = pu[1][2 * ntp + 1][1];
      int key0 = (2 * ntp) * 16 + quad * 4;
      int key1 = (2 * ntp + 1) * 16 + quad * 4;
#pragma unroll
      for (int dt = 0; dt < 4; dt++) {
        int d = dt * 16 + lcol;
        short4v v0 = *(const short4v*)
            &Vts[cur][d * 64 + (((key0 >> 3) ^ (d & 7)) * 8) + (key0 & 7)];
        short4v v1 = *(const short4v*)
            &Vts[cur][d * 64 + (((key1 >> 3) ^ (d & 7)) * 8) + (key1 & 7)];
        short8 vf = {v0[0], v0[1], v0[2], v0[3], v1[0], v1[1], v1[2], v1[3]};
        ot[0][dt] = __builtin_amdgcn_mfma_f32_16x16x32_bf16(vf, pf0.v,
                                                            ot[0][dt], 0, 0, 0);
        ot[1][dt] = __builtin_amdgcn_mfma_f32_16x16x32_bf16(vf, pf1.v,
                                                            ot[1][dt], 0, 0, 0);
      }
    }
  }

#pragma unroll
  for (int qg = 0; qg < 2; qg++) {
    float s = lsum[qg];
    s += __shfl_xor(s, 16);
    s += __shfl_xor(s, 32);
    const float inv = 1.0f / s;
    const int m = q0 + w * 32 + qg * 16 + lcol;
    ushort* orow = o + ((size_t)(b * HW_ + m)) * C_ + h * 64;
#pragma unroll
    for (int dt = 0; dt < 4; dt++) {
      union { unsigned u[2]; ushort4_t s4; } pu2;
      pu2.u[0] = cvt_pk_bf16(ot[qg][dt][0] * inv, ot[qg][dt][1] * inv);
      pu2.u[1] = cvt_pk_bf16(ot[qg][dt][2] * inv, ot[qg][dt][3] * inv);
      *(ushort4_t*)&orow[dt * 16 + quad * 4] = pu2.s4;
    }
  }
}

// -------------------------------------------------------------------------
// K4 (fused): proj GEMM + bias + LayerNorm + residual(xT) -> y_bf.
// 16 tokens x 512 ch per block, grid 512 -> 2 blocks/CU.
// Epilogue: phase 1 stages exact-f32 LN output in swizzled LDS (reusing
// Bs); phase 2 adds resid (coalesced ushort8 reads) and stores ushort8.
__global__ __launch_bounds__(512) void gemm_proj_ln(
    const ushort* __restrict__ A, const ushort* __restrict__ Wm,
    const float* __restrict__ bias, const float* __restrict__ g,
    const float* __restrict__ bb, const ushort* __restrict__ resid,
    ushort* __restrict__ ybf) {
  __shared__ alignas(16) ushort As[2][16 * 32];
  __shared__ alignas(16) ushort Bs[2][512 * 32];
  __shared__ float red[8][16][2];
  const int bm = blockIdx.x * 16;
  const int tid = threadIdx.x;
  const int w = tid >> 6, lane = tid & 63;
  const int l15 = lane & 15, lq = lane >> 4;
  const int srr = lane >> 2, sq1 = lane & 3;

  f32x4 acc[4];
#pragma unroll
  for (int j = 0; j < 4; j++) acc[j] = (f32x4){0.f, 0.f, 0.f, 0.f};

  auto stage = [&](int kt, int bufi) {
#pragma unroll
    for (int it = 0; it < 4; it++) {
      int r = it * 128 + w * 16 + srr;
      int q = (sq1 - (r >> 1)) & 3;
      GLD16(Wm + (size_t)r * C_ + kt * 32 + q * 8,
            &Bs[bufi][(it * 128 + w * 16) * 32]);
    }
    if (w == 0) {
      int r = srr;  // 0..15
      int q = (sq1 - (r >> 1)) & 3;
      GLD16(A + (size_t)(bm + r) * C_ + kt * 32 + q * 8, &As[bufi][0]);
    }
  };

  stage(0, 0);

  for (int ks = 0; ks < 16; ks++) {
    __syncthreads();
    const int cur = ks & 1;
    if (ks + 1 < 16) stage(ks + 1, cur ^ 1);

    short8 af, bf[4];
    {
      int r = l15;
      af = *(const short8*)&As[cur][r * 32 + (((lq + (r >> 1)) & 3) * 8)];
    }
#pragma unroll
    for (int j = 0; j < 4; j++) {
      int c = w * 64 + j * 16 + l15;
      bf[j] = *(const short8*)&Bs[cur][c * 32 + (((lq + (c >> 1)) & 3) * 8)];
    }
#pragma unroll
    for (int j = 0; j < 4; j++)
      acc[j] = __builtin_amdgcn_mfma_f32_16x16x32_bf16(af, bf[j], acc[j],
                                                       0, 0, 0);
  }

  float bv[4];
#pragma unroll
  for (int j = 0; j < 4; j++) bv[j] = bias[w * 64 + j * 16 + l15];

  float s1v[4], s2v[4];
#pragma unroll
  for (int r = 0; r < 4; r++) {
    float a = 0.f, q2 = 0.f;
#pragma unroll
    for (int j = 0; j < 4; j++) {
      float v = acc[j][r] + bv[j];
      acc[j][r] = v;
      a += v;
      q2 += v * v;
    }
    s1v[r] = a;
    s2v[r] = q2;
  }
#pragma unroll
  for (int off = 1; off < 16; off <<= 1) {
#pragma unroll
    for (int r = 0; r < 4; r++) {
      s1v[r] += __shfl_xor(s1v[r], off);
      s2v[r] += __shfl_xor(s2v[r], off);
    }
  }
  if (l15 == 0) {
#pragma unroll
    for (int r = 0; r < 4; r++) {
      int tok = lq * 4 + r;
      red[w][tok][0] = s1v[r];
      red[w][tok][1] = s2v[r];
    }
  }
  __syncthreads();  // also: all Bs reads done -> T may reuse Bs

  float gv[4], bbv[4];
#pragma unroll
  for (int j = 0; j < 4; j++) {
    gv[j] = g[w * 64 + j * 16 + l15];
    bbv[j] = bb[w * 64 + j * 16 + l15];
  }

  // phase 1: LN result (pre-residual, exact f32) -> T, chunk-swizzled
  float* T = (float*)&Bs[0][0];  // 16 tok x 512 ch f32 = 32 KB
#pragma unroll
  for (int r = 0; r < 4; r++) {
    int tok = lq * 4 + r;
    float su = 0.f, sq = 0.f;
#pragma unroll
    for (int ww = 0; ww < 8; ww++) {
      su += red[ww][tok][0];
      sq += red[ww][tok][1];
    }
    float mu = su * (1.0f / C_);
    float var = sq * (1.0f / C_) - mu * mu;
    float rstd = rsqrtf(var + 1e-5f);
    int s = (tok << 3) | (tok & 7);
#pragma unroll
    for (int j = 0; j < 4; j++) {
      int c = w * 64 + j * 16 + l15;
      float y = (acc[j][r] - mu) * rstd * gv[j] + bbv[j];
      int q = c >> 2;
      T[tok * 512 + (((q ^ s) & 127) << 2) + (c & 3)] = y;
    }
  }
  __syncthreads();

  // phase 2: +resid (ushort8), pack, contiguous ushort8 stores.
  const int mrow = tid >> 5, j0 = tid & 31;
  const int s2 = (mrow << 3) | (mrow & 7);
#pragma unroll
  for (int p = 0; p < 2; p++) {
    int c0 = p * 256 + j0 * 8;
    int q0 = c0 >> 2;
    f32x4 a = *(const f32x4*)&T[mrow * 512 + (((q0 ^ s2) & 127) << 2)];
    f32x4 b2 = *(const f32x4*)&T[mrow * 512 + ((((q0 + 1) ^ s2) & 127) << 2)];
    int m = bm + mrow;
    ushort8 r8 = *(const ushort8*)&resid[(size_t)m * C_ + c0];
    union { unsigned u[4]; ushort8 v; } pk;
    pk.u[0] = cvt_pk_bf16(a[0] + bf2f(r8[0]), a[1] + bf2f(r8[1]));
    pk.u[1] = cvt_pk_bf16(a[2] + bf2f(r8[2]), a[3] + bf2f(r8[3]));
    pk.u[2] = cvt_pk_bf16(b2[0] + bf2f(r8[4]), b2[1] + bf2f(r8[5]));
    pk.u[3] = cvt_pk_bf16(b2[2] + bf2f(r8[6]), b2[3] + bf2f(r8[7]));
    *(ushort8*)&ybf[(size_t)m * C_ + c0] = pk.v;
  }
}

// -------------------------------------------------------------------------
// K6: depthwise 3x3 SAME on bf16 y (token-major) -> bf16 out (+dw bias).
// Sliding-window: the thread's 4 tokens share a spatial row (base%4==0,
// 4|32), so the 3x6 tap window is loaded once (18 loads, was 36); each
// load feeds up to 3 tokens. Accumulation order per token unchanged
// (kx ascends within each ky) -> bit-identical.
__global__ __launch_bounds__(256) void dwconv_kernel(
    const ushort* __restrict__ y, const float* __restrict__ w,
    const float* __restrict__ bias, ushort* __restrict__ out) {
  const int cg = threadIdx.x & 63, tg = threadIdx.x >> 6;
  const int c0 = cg * 8;
  float wreg[9][8], breg[8];
#pragma unroll
  for (int j = 0; j < 8; j++) {
    breg[j] = bias[c0 + j];
#pragma unroll
    for (int kk = 0; kk < 9; kk++) wreg[kk][j] = w[(c0 + j) * 9 + kk];
  }
  const int base = blockIdx.x * 16 + tg * 4;
  const int b = base >> 10, s = base & (HW_ - 1);
  const int hh = s >> 5, w0 = s & 31;
  float acc[4][8];
#pragma unroll
  for (int i = 0; i < 4; i++)
#pragma unroll
    for (int j = 0; j < 8; j++) acc[i][j] = breg[j];
#pragma unroll
  for (int ky = 0; ky < 3; ky++) {
    int yy = hh + ky - 1;
    if (yy < 0 || yy >= HH_) continue;
    const ushort* yrow = &y[((size_t)(b * HW_ + yy * 32)) * C_ + c0];
#pragma unroll
    for (int xx6 = 0; xx6 < 6; xx6++) {
      int xx = w0 - 1 + xx6;
      if (xx < 0 || xx >= WW_) continue;  // wave-uniform branch
      ushort8 v8 = *(const ushort8*)&yrow[(size_t)xx * C_];
      float vf[8];
#pragma unroll
      for (int j = 0; j < 8; j++) vf[j] = bf2f(v8[j]);
#pragma unroll
      for (int i = 0; i < 4; i++) {
        int kx = xx6 - i;  // tap index for token i
        if (kx < 0 || kx > 2) continue;
        const float* wk = wreg[ky * 3 + kx];
#pragma unroll
        for (int j = 0; j < 8; j++) acc[i][j] += wk[j] * vf[j];
      }
    }
  }
#pragma unroll
  for (int i = 0; i < 4; i++) {
    union { unsigned u[4]; ushort8 v; } pku;
    pku.u[0] = cvt_pk_bf16(acc[i][0], acc[i][1]);
    pku.u[1] = cvt_pk_bf16(acc[i][2], acc[i][3]);
    pku.u[2] = cvt_pk_bf16(acc[i][4], acc[i][5]);
    pku.u[3] = cvt_pk_bf16(acc[i][6], acc[i][7]);
    *(ushort8*)&out[(size_t)(base + i) * C_ + c0] = pku.v;
  }
}

// -------------------------------------------------------------------------
extern "C" void kernel_launch(void* const* d_in, const int* in_sizes, int n_in,
                              void* d_out, int out_size, void* d_ws,
                              size_t ws_size, hipStream_t stream) {
  const float* x = (const float*)d_in[0];
  const float* qkv_w = (const float*)d_in[1];
  const float* proj_w = (const float*)d_in[2];
  const float* proj_b = (const float*)d_in[3];
  const float* temperature = (const float*)d_in[4];
  const float* ln_g = (const float*)d_in[5];
  const float* ln_b = (const float*)d_in[6];
  const float* pos = (const float*)d_in[7];
  const float* dw_w = (const float*)d_in[8];
  const float* dw_b = (const float*)d_in[9];
  const float* pw_w = (const float*)d_in[10];
  const float* pw_b = (const float*)d_in[11];
  float* out = (float*)d_out;

  float* ws = (float*)d_ws;
  ushort* qkv_bf = (ushort*)ws;
  ushort* t_bf = (ushort*)(ws + (size_t)6 * 1024 * 1024);
  ushort* xT_bf = (ushort*)(ws + (size_t)12 * 1024 * 1024);
  ushort* wts = (ushort*)(ws + (size_t)14 * 1024 * 1024);
  ushort* qkvw_bf = wts;
  ushort* projw_bf = wts + 786432;
  ushort* pww_bf = wts + 1048576;
  float* sums = ws + (size_t)15 * 1024 * 1024;
  float* qsum = sums;
  float* ksum = sums + 4096;
  ushort* vtb = (ushort*)(ws + (size_t)16 * 1024 * 1024);

  const int M = BB_ * HW_;  // 8192 tokens

  // 1) prep: weights->bf16 (x4 vec), t/xT transpose, zero sums
  prep_kernel<<<2336, 256, 0, stream>>>(x, pos, qkv_w, proj_w, pw_w, t_bf,
                                        xT_bf, wts, sums);
  // 2) qkv GEMM (BK=64, XCD-local bm, LDS-staged q/k + V stores)
  gemm_qkv<<<dim3(C3_ / 128, M / 128), 256, 0, stream>>>(
      t_bf, qkvw_bf, qkv_bf, vtb, qsum, ksum);
  // 3) flash attention (128q/block, K=32 PV via fragment concat) -> attn_out
  attn_mfma_kernel<<<BB_ * NH_ * (HW_ / 128), 256, 0, stream>>>(
      qkv_bf, vtb, qsum, ksum, temperature, t_bf);
  // 4+5) fused proj GEMM + bias + LayerNorm + residual -> y_bf (over xT)
  gemm_proj_ln<<<M / 16, 512, 0, stream>>>(t_bf, projw_bf, proj_b, ln_g,
                                           ln_b, xT_bf, xT_bf);
  // 6) depthwise 3x3 (sliding-window) on bf16 y -> dw_out (reuses t region)
  dwconv_kernel<<<M / 16, 256, 0, stream>>>(xT_bf, dw_w, dw_b, t_bf);
  // 7) pointwise GEMM (BK=64, XCD-local bm) + pw_b + residual, NCHW -> out
  gemm_n64<2><<<dim3(C_ / 64, M / 128), 256, 0, stream>>>(
      t_bf, pww_bf, pw_b, out, xT_bf, C_, C_);
}

// Round 10
// 181.153 us; speedup vs baseline: 1.0861x; 1.0350x over previous
//
#include <hip/hip_runtime.h>
#include <math.h>

// Problem constants
#define BB_ 8
#define C_ 512
#define C3_ 1536
#define HW_ 1024
#define NH_ 8
#define DH_ 64
#define HH_ 32
#define WW_ 32

typedef __attribute__((ext_vector_type(8))) short short8;
typedef __attribute__((ext_vector_type(4))) short short4v;
typedef __attribute__((ext_vector_type(8))) unsigned short ushort8;
typedef __attribute__((ext_vector_type(4))) unsigned short ushort4_t;
typedef __attribute__((ext_vector_type(4))) float f32x4;
typedef unsigned short ushort;

__device__ inline ushort f2bf(float f) {
  union { float f; unsigned u; } v;
  v.f = f;
  unsigned r = v.u + 0x7fffu + ((v.u >> 16) & 1u);
  return (ushort)(r >> 16);
}
__device__ inline float bf2f(ushort u) {
  union { unsigned u; float f; } v;
  v.u = ((unsigned)u) << 16;
  return v.f;
}

// One-instruction RNE pack of two f32 -> two bf16 (lo=a, hi=b).
__device__ inline unsigned cvt_pk_bf16(float a, float b) {
  unsigned r;
  asm("v_cvt_pk_bf16_f32 %0, %1, %2" : "=v"(r) : "v"(a), "v"(b));
  return r;
}

__device__ inline float fast_exp2(float x) {
#if __has_builtin(__builtin_amdgcn_exp2f)
  return __builtin_amdgcn_exp2f(x);
#else
  return exp2f(x);
#endif
}

#define GLD16(gptr, lptr)                                                     \
  __builtin_amdgcn_global_load_lds(                                           \
      (const __attribute__((address_space(1))) unsigned int*)(gptr),          \
      (__attribute__((address_space(3))) unsigned int*)(lptr), 16, 0, 0)

// -------------------------------------------------------------------------
// K1 (prep): fused weight-cvt (x4 vectorized) + x transpose(+pos) +
// qsum/ksum zeroing. Grid: 1024 transpose + 1280 wcvt + 32 sums = 2336.
__global__ __launch_bounds__(256) void prep_kernel(
    const float* __restrict__ x, const float* __restrict__ pos,
    const float* __restrict__ qkv_w, const float* __restrict__ proj_w,
    const float* __restrict__ pw_w, ushort* __restrict__ t,
    ushort* __restrict__ xT, ushort* __restrict__ wts,
    float* __restrict__ sums) {
  const int bid = blockIdx.x;
  const int tid = threadIdx.x;
  if (bid >= 2304) {
    sums[(bid - 2304) * 256 + tid] = 0.f;
    return;
  }
  if (bid >= 1024) {
    int i = ((bid - 1024) * 256 + tid) * 4;
    float4 v;
    if (i < 786432) v = *(const float4*)&qkv_w[i];
    else if (i < 1048576) v = *(const float4*)&proj_w[i - 786432];
    else v = *(const float4*)&pw_w[i - 1048576];
    union { unsigned u[2]; ushort4_t s; } o4;
    o4.u[0] = cvt_pk_bf16(v.x, v.y);
    o4.u[1] = cvt_pk_bf16(v.z, v.w);
    *(ushort4_t*)&wts[i] = o4.s;
    return;
  }
  __shared__ float tile[64][65];
  const int n0 = (bid & 15) * 64, c0 = ((bid >> 4) & 7) * 64, b = bid >> 7;
#pragma unroll
  for (int it = 0; it < 4; it++) {
    int c_l = (tid >> 4) + it * 16;
    int n_l4 = (tid & 15) * 4;
    float4 v = *(const float4*)&x[((size_t)(b * C_ + c0 + c_l)) * HW_ + n0 + n_l4];
    tile[c_l][n_l4 + 0] = v.x;
    tile[c_l][n_l4 + 1] = v.y;
    tile[c_l][n_l4 + 2] = v.z;
    tile[c_l][n_l4 + 3] = v.w;
  }
  __syncthreads();
#pragma unroll
  for (int it = 0; it < 4; it++) {
    int n_l = (tid >> 4) + it * 16;
    int c_l4 = (tid & 15) * 4;
    size_t token = (size_t)(b * HW_ + n0 + n_l);
    float4 pv = *(const float4*)&pos[(n0 + n_l) * C_ + c0 + c_l4];
    float xv0 = tile[c_l4 + 0][n_l], xv1 = tile[c_l4 + 1][n_l];
    float xv2 = tile[c_l4 + 2][n_l], xv3 = tile[c_l4 + 3][n_l];
    ushort4_t tb = {f2bf(xv0 + pv.x), f2bf(xv1 + pv.y), f2bf(xv2 + pv.z),
                    f2bf(xv3 + pv.w)};
    ushort4_t xb = {f2bf(xv0), f2bf(xv1), f2bf(xv2), f2bf(xv3)};
    *(ushort4_t*)&t[token * C_ + c0 + c_l4] = tb;
    *(ushort4_t*)&xT[token * C_ + c0 + c_l4] = xb;
  }
}

// -------------------------------------------------------------------------
// K2: qkv GEMM, BK=64 (8 K-steps). Row-swizzled 8-chunk LDS. XCD-local bm.
// Both epilogues stage through LDS (reusing As+Bs) for contiguous ushort8
// global stores.
__global__ __launch_bounds__(256) void gemm_qkv(
    const ushort* __restrict__ A, const ushort* __restrict__ Wm,
    ushort* __restrict__ out, ushort* __restrict__ vt,
    float* __restrict__ qsum, float* __restrict__ ksum) {
  const int N = C3_, K = C_;
  __shared__ alignas(16) ushort smem[2 * 128 * 64];
  ushort* As = smem;
  ushort* Bs = smem + 128 * 64;
  const int f = blockIdx.y * gridDim.x + blockIdx.x;  // 0..767
  const int xcd = f & 7, idx = f >> 3;                // idx 0..95
  const int bm = (xcd * 8 + idx / 12) * 128;
  const int bn = (idx % 12) * 128;
  const int tid = threadIdx.x;
  const int w = tid >> 6, lane = tid & 63;
  const int wm = 64 * (w & 1), wn = 64 * (w >> 1);
  const int l15 = lane & 15, lq = lane >> 4;

  f32x4 acc[4][4];
#pragma unroll
  for (int i = 0; i < 4; i++)
#pragma unroll
    for (int j = 0; j < 4; j++) acc[i][j] = (f32x4){0.f, 0.f, 0.f, 0.f};

  const int srr8 = lane >> 3, sq3 = lane & 7;

  for (int k0 = 0; k0 < K; k0 += 64) {
    __syncthreads();
#pragma unroll
    for (int it = 0; it < 4; it++) {
      int r = w * 32 + it * 8 + srr8;
      int g = (sq3 - r) & 7;
      GLD16(A + (size_t)(bm + r) * K + k0 + g * 8, &As[(w * 32 + it * 8) * 64]);
      GLD16(Wm + (size_t)(bn + r) * K + k0 + g * 8, &Bs[(w * 32 + it * 8) * 64]);
    }
    __syncthreads();
#pragma unroll
    for (int kk = 0; kk < 2; kk++) {
      short8 af[4], bf[4];
#pragma unroll
      for (int nt = 0; nt < 4; nt++) {
        int r = wm + nt * 16 + l15;
        af[nt] = *(const short8*)&As[r * 64 + (((kk * 4 + lq) + r) & 7) * 8];
        int c = wn + nt * 16 + l15;
        bf[nt] = *(const short8*)&Bs[c * 64 + (((kk * 4 + lq) + c) & 7) * 8];
      }
#pragma unroll
      for (int i = 0; i < 4; i++)
#pragma unroll
        for (int j = 0; j < 4; j++)
          acc[i][j] = __builtin_amdgcn_mfma_f32_16x16x32_bf16(
              af[i], bf[j], acc[i][j], 0, 0, 0);
    }
  }

  const int b = bm >> 10;
  if (bn < 1024) {
    __syncthreads();  // all LDS reads of As/Bs done before T reuse
    ushort* T = smem;  // 128m x 128c bf16, chunk-swizzled
#pragma unroll
    for (int j = 0; j < 4; j++) {
      int c_l = wn + j * 16 + l15;
      int c = bn + c_l;
      float ss = 0.f;
#pragma unroll
      for (int i = 0; i < 4; i++) {
#pragma unroll
        for (int r = 0; r < 4; r++) {
          int m_l = wm + i * 16 + lq * 4 + r;
          float v = acc[i][j][r];
          ss += v * v;
          T[m_l * 128 + (((c_l >> 3) ^ (m_l & 15)) << 3) + (c_l & 7)] =
              f2bf(v);
        }
      }
      ss += __shfl_xor(ss, 16);
      ss += __shfl_xor(ss, 32);
      if (lq == 0) {
        if (c < 512) atomicAdd(&qsum[b * 512 + c], ss);
        else atomicAdd(&ksum[b * 512 + c - 512], ss);
      }
    }
    __syncthreads();
    const int jj = tid & 15, mrow = tid >> 4;
#pragma unroll
    for (int p = 0; p < 8; p++) {
      int m_l = p * 16 + mrow;
      ushort8 v8 = *(const ushort8*)&T[m_l * 128 + ((jj ^ (m_l & 15)) << 3)];
      *(ushort8*)&out[(size_t)(bm + m_l) * N + bn + jj * 8] = v8;
    }
  } else {
    // V: stage 128c x 128n transposed tile in LDS -> contiguous stores.
    __syncthreads();  // all LDS reads of As/Bs done before T reuse
    ushort* T = smem;  // 128c x 128n bf16, chunk-swizzled on n
#pragma unroll
    for (int j = 0; j < 4; j++) {
      int c_l = wn + j * 16 + l15;  // local d-channel row
#pragma unroll
      for (int i = 0; i < 4; i++) {
        int n_l = wm + i * 16 + lq * 4;  // local token, 4 consecutive
        union { unsigned u[2]; ushort4_t s; } pu;
        pu.u[0] = cvt_pk_bf16(acc[i][j][0], acc[i][j][1]);
        pu.u[1] = cvt_pk_bf16(acc[i][j][2], acc[i][j][3]);
        *(ushort4_t*)&T[c_l * 128 + (((n_l >> 3) ^ (c_l & 15)) << 3) +
                        (n_l & 7)] = pu.s;
      }
    }
    __syncthreads();
    const int jj = tid & 15, crow = tid >> 4;
    const int n0 = bm & 1023;
#pragma unroll
    for (int p = 0; p < 8; p++) {
      int c_l = p * 16 + crow;
      ushort8 v8 = *(const ushort8*)&T[c_l * 128 + ((jj ^ (c_l & 15)) << 3)];
      int hd = bn - 1024 + c_l;
      *(ushort8*)&vt[((size_t)(b * 512 + hd)) * HW_ + n0 + jj * 8] = v8;
    }
  }
}

// -------------------------------------------------------------------------
// bf16 MFMA GEMM 128x64 tiles, BK=64 (8 K-steps), single-buffered.
// XCD-locality remap. EPI 1 (proj): bf16 +bias token-major, staged via
// swizzled LDS -> contiguous ushort8 stores. EPI 2 (pointwise conv):
// f32 +bias +resid(bf16), NCHW store staged via swizzled LDS -> dwordx4.
template <int EPI>
__global__ __launch_bounds__(256) void gemm_n64(
    const ushort* __restrict__ A, const ushort* __restrict__ Wm,
    const float* __restrict__ bias, void* __restrict__ outv,
    const ushort* __restrict__ resid, int N, int K) {
  __shared__ alignas(16) ushort As[128 * 64];
  __shared__ alignas(16) ushort Bs[64 * 64];
  __shared__ alignas(16) float Cs[EPI == 2 ? 64 * 128 : 64 * 64];
  const int f = blockIdx.y * gridDim.x + blockIdx.x;
  const int xcd = f & 7, idx = f >> 3;
  const int nbx = gridDim.x;
  const int bm = (xcd * (gridDim.y >> 3) + idx / nbx) * 128;
  const int bn = (idx % nbx) * 64;
  const int tid = threadIdx.x;
  const int w = tid >> 6, lane = tid & 63;
  const int wm = 64 * (w & 1), wn = 32 * (w >> 1);
  const int l15 = lane & 15, lq = lane >> 4;

  f32x4 acc[4][2];
#pragma unroll
  for (int i = 0; i < 4; i++)
#pragma unroll
    for (int j = 0; j < 2; j++) acc[i][j] = (f32x4){0.f, 0.f, 0.f, 0.f};

  const int srr8 = lane >> 3, sq3 = lane & 7;

  for (int k0 = 0; k0 < K; k0 += 64) {
    __syncthreads();
#pragma unroll
    for (int it = 0; it < 4; it++) {
      int r = w * 32 + it * 8 + srr8;
      int g = (sq3 - r) & 7;
      GLD16(A + (size_t)(bm + r) * K + k0 + g * 8, &As[(w * 32 + it * 8) * 64]);
    }
#pragma unroll
    for (int it = 0; it < 2; it++) {
      int r = w * 16 + it * 8 + srr8;
      int g = (sq3 - r) & 7;
      GLD16(Wm + (size_t)(bn + r) * K + k0 + g * 8, &Bs[(w * 16 + it * 8) * 64]);
    }
    __syncthreads();
#pragma unroll
    for (int kk = 0; kk < 2; kk++) {
      short8 af[4], bf[2];
#pragma unroll
      for (int nt = 0; nt < 4; nt++) {
        int r = wm + nt * 16 + l15;
        af[nt] = *(const short8*)&As[r * 64 + (((kk * 4 + lq) + r) & 7) * 8];
      }
#pragma unroll
      for (int j = 0; j < 2; j++) {
        int c = wn + j * 16 + l15;
        bf[j] = *(const short8*)&Bs[c * 64 + (((kk * 4 + lq) + c) & 7) * 8];
      }
#pragma unroll
      for (int i = 0; i < 4; i++)
#pragma unroll
        for (int j = 0; j < 2; j++)
          acc[i][j] = __builtin_amdgcn_mfma_f32_16x16x32_bf16(
              af[i], bf[j], acc[i][j], 0, 0, 0);
    }
  }

  if (EPI == 1) {
    // Stage 128m x 64c bf16 tile (chunk-swizzled) -> ushort8 stores.
    ushort* Tc = (ushort*)Cs;
#pragma unroll
    for (int i = 0; i < 4; i++) {
#pragma unroll
      for (int j = 0; j < 2; j++) {
        int c_l = wn + j * 16 + l15;
        float bv = bias[bn + c_l];
#pragma unroll
        for (int r = 0; r < 4; r++) {
          int m_l = wm + i * 16 + lq * 4 + r;
          Tc[m_l * 64 + (((c_l >> 3) ^ (m_l & 7)) << 3) + (c_l & 7)] =
              f2bf(acc[i][j][r] + bv);
        }
      }
    }
    __syncthreads();
    const int jj = tid & 7, mrow = tid >> 3;  // 32 rows/pass
#pragma unroll
    for (int p = 0; p < 4; p++) {
      int m_l = p * 32 + mrow;
      ushort8 v8 = *(const ushort8*)&Tc[m_l * 64 + ((jj ^ (m_l & 7)) << 3)];
      *(ushort8*)&((ushort*)outv)[(size_t)(bm + m_l) * N + bn + jj * 8] = v8;
    }
  } else {
    // Phase 1: acc(+bias+resid) -> Cs[c][m], float4 chunks XOR-swizzled.
#pragma unroll
    for (int i = 0; i < 4; i++) {
#pragma unroll
      for (int j = 0; j < 2; j++) {
        int c_l = wn + j * 16 + l15;
        int m_l = wm + i * 16 + lq * 4;
        float bv = bias[bn + c_l];
        f32x4 vv;
#pragma unroll
        for (int r = 0; r < 4; r++) {
          int m = bm + m_l + r;
          vv[r] = acc[i][j][r] + bv + bf2f(resid[(size_t)m * C_ + bn + c_l]);
        }
        int phys = (m_l >> 2) ^ (c_l & 31);
        *(f32x4*)&Cs[c_l * 128 + phys * 4] = vv;
      }
    }
    __syncthreads();
    // Phase 2: per c-row contiguous 512B stores (dwordx4, 32 lanes/row).
    const int b = bm >> 10, s0 = bm & (HW_ - 1);
    const int l5 = tid & 31;
    const int rr = tid >> 5;  // 0..7
    float* outp = (float*)outv;
#pragma unroll
    for (int pass = 0; pass < 8; pass++) {
      int row = rr + pass * 8;  // local c in [0,64)
      int phys = l5 ^ (row & 31);
      f32x4 vv = *(const f32x4*)&Cs[row * 128 + phys * 4];
      *(f32x4*)&outp[((size_t)(b * C_ + bn + row)) * HW_ + s0 + l5 * 4] = vv;
    }
  }
}

// -------------------------------------------------------------------------
// K3: MFMA flash attention, 32 queries/wave (128q/block, grid 512),
// bh-minor XCD-local order. K=32 PV via fragment concatenation.
__global__ __launch_bounds__(256) void attn_mfma_kernel(
    const ushort* __restrict__ qkv, const ushort* __restrict__ vt,
    const float* __restrict__ qsum, const float* __restrict__ ksum,
    const float* __restrict__ temp, ushort* __restrict__ o) {
  __shared__ alignas(16) ushort Ks[2][64 * 64];   // [key][d], chunk-swizzled
  __shared__ alignas(16) ushort Vts[2][64 * 64];  // [d][key], chunk-swizzled
  __shared__ float sc_lds[64];

  const int tid = threadIdx.x;
  const int w = tid >> 6, lane = tid & 63;
  const int quad = lane >> 4, lcol = lane & 15;
  const int bh = blockIdx.x & 63;   // XCD-locality: bh determines XCD
  const int qt = blockIdx.x >> 6;   // 0..7
  const int b = bh >> 3, h = bh & 7;
  const int q0 = qt * 128;

  if (tid < 64) {
    float qs = qsum[b * 512 + h * 64 + tid];
    float ks = ksum[b * 512 + h * 64 + tid];
    float iq = 1.0f / fmaxf(sqrtf(qs), 1e-12f);
    float ik = 1.0f / fmaxf(sqrtf(ks), 1e-12f);
    sc_lds[tid] = iq * ik * temp[h] * 1.44269504088896340736f;  // fold log2e
  }

  const ushort* kg = qkv + (size_t)b * HW_ * C3_ + C_ + h * 64;
  const ushort* vg = vt + (size_t)(bh * 64) * HW_;

  // staging: 256 threads x 2 iters cover 64 rows x 8 chunks (of 8 bf16)
  const int srow0 = tid >> 3;  // 0..31
  const int sc = tid & 7;

  // prologue: stage tile 0 into buffer 0
#pragma unroll
  for (int it = 0; it < 2; it++) {
    int row = srow0 + it * 32;
    int scg = sc ^ (row & 7);
    GLD16(kg + (size_t)row * C3_ + scg * 8, &Ks[0][w * 512 + it * 2048]);
    GLD16(vg + (size_t)row * HW_ + scg * 8, &Vts[0][w * 512 + it * 2048]);
  }
  __syncthreads();

  // Q fragments for both q-groups (B-operand of S^T = K·Q^T), scales folded.
  short8 qf[2][2];
#pragma unroll
  for (int qg = 0; qg < 2; qg++) {
    const int m = q0 + w * 32 + qg * 16 + lcol;
    const ushort* qrow = qkv + ((size_t)(b * HW_ + m)) * C3_ + h * 64;
#pragma unroll
    for (int kc = 0; kc < 2; kc++) {
      ushort8 q8 = *(const ushort8*)&qrow[kc * 32 + quad * 8];
      union { short8 v; ushort u[8]; } pk;
#pragma unroll
      for (int j = 0; j < 8; j++) {
        int d = kc * 32 + quad * 8 + j;
        pk.u[j] = f2bf(bf2f(q8[j]) * sc_lds[d]);
      }
      qf[qg][kc] = pk.v;
    }
  }

  f32x4 ot[2][4];
#pragma unroll
  for (int qg = 0; qg < 2; qg++)
#pragma unroll
    for (int dt = 0; dt < 4; dt++) ot[qg][dt] = (f32x4){0.f, 0.f, 0.f, 0.f};
  float lsum[2] = {0.f, 0.f};

  for (int kt = 0; kt < 16; kt++) {
    if (kt > 0) __syncthreads();  // drains GLD(kt) + prior buffer reads
    const int cur = kt & 1;
    if (kt + 1 < 16) {
      const int nxt = cur ^ 1;
#pragma unroll
      for (int it = 0; it < 2; it++) {
        int row = srow0 + it * 32;
        int scg = sc ^ (row & 7);
        GLD16(kg + (size_t)((kt + 1) * 64 + row) * C3_ + scg * 8,
              &Ks[nxt][w * 512 + it * 2048]);
        GLD16(vg + (size_t)row * HW_ + (kt + 1) * 64 + scg * 8,
              &Vts[nxt][w * 512 + it * 2048]);
      }
    }

    // S^T = K·Q^T for both q-groups; each K fragment read used twice
    f32x4 sfr[2][4];
#pragma unroll
    for (int qg = 0; qg < 2; qg++)
#pragma unroll
      for (int nt = 0; nt < 4; nt++) sfr[qg][nt] = (f32x4){0.f, 0.f, 0.f, 0.f};
#pragma unroll
    for (int kc = 0; kc < 2; kc++) {
#pragma unroll
      for (int nt = 0; nt < 4; nt++) {
        int row = nt * 16 + lcol;
        short8 kf = *(const short8*)
            &Ks[cur][row * 64 + (((kc * 4 + quad) ^ (row & 7)) * 8)];
        sfr[0][nt] = __builtin_amdgcn_mfma_f32_16x16x32_bf16(kf, qf[0][kc],
                                                             sfr[0][nt], 0, 0, 0);
        sfr[1][nt] = __builtin_amdgcn_mfma_f32_16x16x32_bf16(kf, qf[1][kc],
                                                             sfr[1][nt], 0, 0, 0);
      }
    }

    // exp2 + per-lane sum + pack P pairs via cvt_pk
    unsigned pu[2][4][2];
#pragma unroll
    for (int qg = 0; qg < 2; qg++) {
#pragma unroll
      for (int nt = 0; nt < 4; nt++) {
        float f0 = fast_exp2(sfr[qg][nt][0]);
        float f1 = fast_exp2(sfr[qg][nt][1]);
        float f2 = fast_exp2(sfr[qg][nt][2]);
        float f3 = fast_exp2(sfr[qg][nt][3]);
        lsum[qg] += f0 + f1 + f2 + f3;
        pu[qg][nt][0] = cvt_pk_bf16(f0, f1);
        pu[qg][nt][1] = cvt_pk_bf16(f2, f3);
      }
    }

    // O^T += V^T · P^T with K=32 MFMA (fragment concat, register-local).
#pragma unroll
    for (int ntp = 0; ntp < 2; ntp++) {
      union { unsigned u[4]; short8 v; } pf0, pf1;
      pf0.u[0] = pu[0][2 * ntp][0];
      pf0.u[1] = pu[0][2 * ntp][1];
      pf0.u[2] = pu[0][2 * ntp + 1][0];
      pf0.u[3] = pu[0][2 * ntp + 1][1];
      pf1.u[0] = pu[1][2 * ntp][0];
      pf1.u[1] = pu[1][2 * ntp][1];
      pf1.u[2] = pu[1][2 * ntp + 1][0];
      pf1.u[3] = pu[1][2 * ntp + 1][1];
      int key0 = (2 * ntp) * 16 + quad * 4;
      int key1 = (2 * ntp + 1) * 16 + quad * 4;
#pragma unroll
      for (int dt = 0; dt < 4; dt++) {
        int d = dt * 16 + lcol;
        short4v v0 = *(const short4v*)
            &Vts[cur][d * 64 + (((key0 >> 3) ^ (d & 7)) * 8) + (key0 & 7)];
        short4v v1 = *(const short4v*)
            &Vts[cur][d * 64 + (((key1 >> 3) ^ (d & 7)) * 8) + (key1 & 7)];
        short8 vf = {v0[0], v0[1], v0[2], v0[3], v1[0], v1[1], v1[2], v1[3]};
        ot[0][dt] = __builtin_amdgcn_mfma_f32_16x16x32_bf16(vf, pf0.v,
                                                            ot[0][dt], 0, 0, 0);
        ot[1][dt] = __builtin_amdgcn_mfma_f32_16x16x32_bf16(vf, pf1.v,
                                                            ot[1][dt], 0, 0, 0);
      }
    }
  }

#pragma unroll
  for (int qg = 0; qg < 2; qg++) {
    float s = lsum[qg];
    s += __shfl_xor(s, 16);
    s += __shfl_xor(s, 32);
    const float inv = 1.0f / s;
    const int m = q0 + w * 32 + qg * 16 + lcol;
    ushort* orow = o + ((size_t)(b * HW_ + m)) * C_ + h * 64;
#pragma unroll
    for (int dt = 0; dt < 4; dt++) {
      union { unsigned u[2]; ushort4_t s4; } pu2;
      pu2.u[0] = cvt_pk_bf16(ot[qg][dt][0] * inv, ot[qg][dt][1] * inv);
      pu2.u[1] = cvt_pk_bf16(ot[qg][dt][2] * inv, ot[qg][dt][3] * inv);
      *(ushort4_t*)&orow[dt * 16 + quad * 4] = pu2.s4;
    }
  }
}

// -------------------------------------------------------------------------
// K5: LayerNorm + residual, wave-per-token (no LDS, no barriers).
// bf16 in (proj out) / bf16 residual xT -> bf16 y (in place over xT).
__global__ __launch_bounds__(256) void ln_residual_kernel(
    const ushort* __restrict__ po, const ushort* xT,
    const float* __restrict__ g, const float* __restrict__ bb, ushort* ybf) {
  const int wv = threadIdx.x >> 6, lane = threadIdx.x & 63;
  const int token = blockIdx.x * 4 + wv;
  const int c0 = lane * 8;
  ushort8 p8 = *(const ushort8*)&po[(size_t)token * C_ + c0];
  float v[8];
  float s = 0.f;
#pragma unroll
  for (int j = 0; j < 8; j++) {
    v[j] = bf2f(p8[j]);
    s += v[j];
  }
#pragma unroll
  for (int off = 32; off; off >>= 1) s += __shfl_xor(s, off);
  float mu = s * (1.0f / C_);
  float vs = 0.f;
#pragma unroll
  for (int j = 0; j < 8; j++) {
    v[j] -= mu;
    vs += v[j] * v[j];
  }
#pragma unroll
  for (int off = 32; off; off >>= 1) vs += __shfl_xor(vs, off);
  float rstd = rsqrtf(vs * (1.0f / C_) + 1e-5f);
  float4 g0 = *(const float4*)&g[c0], g1 = *(const float4*)&g[c0 + 4];
  float4 b0 = *(const float4*)&bb[c0], b1 = *(const float4*)&bb[c0 + 4];
  ushort8 r8 = *(const ushort8*)&xT[(size_t)token * C_ + c0];
  float gg[8] = {g0.x, g0.y, g0.z, g0.w, g1.x, g1.y, g1.z, g1.w};
  float bbv[8] = {b0.x, b0.y, b0.z, b0.w, b1.x, b1.y, b1.z, b1.w};
  union { unsigned u[4]; ushort8 v; } pk;
#pragma unroll
  for (int j = 0; j < 4; j++)
    pk.u[j] = cvt_pk_bf16(v[2 * j] * rstd * gg[2 * j] + bbv[2 * j] +
                              bf2f(r8[2 * j]),
                          v[2 * j + 1] * rstd * gg[2 * j + 1] +
                              bbv[2 * j + 1] + bf2f(r8[2 * j + 1]));
  *(ushort8*)&ybf[(size_t)token * C_ + c0] = pk.v;
}

// -------------------------------------------------------------------------
// K6: depthwise 3x3 SAME on bf16 y (token-major) -> bf16 out (+dw bias).
// Sliding-window: the thread's 4 tokens share a spatial row, so the 3x6
// tap window is loaded once (18 loads, was 36).
__global__ __launch_bounds__(256) void dwconv_kernel(
    const ushort* __restrict__ y, const float* __restrict__ w,
    const float* __restrict__ bias, ushort* __restrict__ out) {
  const int cg = threadIdx.x & 63, tg = threadIdx.x >> 6;
  const int c0 = cg * 8;
  float wreg[9][8], breg[8];
#pragma unroll
  for (int j = 0; j < 8; j++) {
    breg[j] = bias[c0 + j];
#pragma unroll
    for (int kk = 0; kk < 9; kk++) wreg[kk][j] = w[(c0 + j) * 9 + kk];
  }
  const int base = blockIdx.x * 16 + tg * 4;
  const int b = base >> 10, s = base & (HW_ - 1);
  const int hh = s >> 5, w0 = s & 31;
  float acc[4][8];
#pragma unroll
  for (int i = 0; i < 4; i++)
#pragma unroll
    for (int j = 0; j < 8; j++) acc[i][j] = breg[j];
#pragma unroll
  for (int ky = 0; ky < 3; ky++) {
    int yy = hh + ky - 1;
    if (yy < 0 || yy >= HH_) continue;
    const ushort* yrow = &y[((size_t)(b * HW_ + yy * 32)) * C_ + c0];
#pragma unroll
    for (int xx6 = 0; xx6 < 6; xx6++) {
      int xx = w0 - 1 + xx6;
      if (xx < 0 || xx >= WW_) continue;  // wave-uniform branch
      ushort8 v8 = *(const ushort8*)&yrow[(size_t)xx * C_];
      float vf[8];
#pragma unroll
      for (int j = 0; j < 8; j++) vf[j] = bf2f(v8[j]);
#pragma unroll
      for (int i = 0; i < 4; i++) {
        int kx = xx6 - i;  // tap index for token i
        if (kx < 0 || kx > 2) continue;
        const float* wk = wreg[ky * 3 + kx];
#pragma unroll
        for (int j = 0; j < 8; j++) acc[i][j] += wk[j] * vf[j];
      }
    }
  }
#pragma unroll
  for (int i = 0; i < 4; i++) {
    union { unsigned u[4]; ushort8 v; } pku;
    pku.u[0] = cvt_pk_bf16(acc[i][0], acc[i][1]);
    pku.u[1] = cvt_pk_bf16(acc[i][2], acc[i][3]);
    pku.u[2] = cvt_pk_bf16(acc[i][4], acc[i][5]);
    pku.u[3] = cvt_pk_bf16(acc[i][6], acc[i][7]);
    *(ushort8*)&out[(size_t)(base + i) * C_ + c0] = pku.v;
  }
}

// -------------------------------------------------------------------------
extern "C" void kernel_launch(void* const* d_in, const int* in_sizes, int n_in,
                              void* d_out, int out_size, void* d_ws,
                              size_t ws_size, hipStream_t stream) {
  const float* x = (const float*)d_in[0];
  const float* qkv_w = (const float*)d_in[1];
  const float* proj_w = (const float*)d_in[2];
  const float* proj_b = (const float*)d_in[3];
  const float* temperature = (const float*)d_in[4];
  const float* ln_g = (const float*)d_in[5];
  const float* ln_b = (const float*)d_in[6];
  const float* pos = (const float*)d_in[7];
  const float* dw_w = (const float*)d_in[8];
  const float* dw_b = (const float*)d_in[9];
  const float* pw_w = (const float*)d_in[10];
  const float* pw_b = (const float*)d_in[11];
  float* out = (float*)d_out;

  float* ws = (float*)d_ws;
  ushort* qkv_bf = (ushort*)ws;
  ushort* t_bf = (ushort*)(ws + (size_t)6 * 1024 * 1024);
  ushort* proj_bf = (ushort*)(ws + (size_t)8 * 1024 * 1024);
  ushort* xT_bf = (ushort*)(ws + (size_t)12 * 1024 * 1024);
  ushort* wts = (ushort*)(ws + (size_t)14 * 1024 * 1024);
  ushort* qkvw_bf = wts;
  ushort* projw_bf = wts + 786432;
  ushort* pww_bf = wts + 1048576;
  float* sums = ws + (size_t)15 * 1024 * 1024;
  float* qsum = sums;
  float* ksum = sums + 4096;
  ushort* vtb = (ushort*)(ws + (size_t)16 * 1024 * 1024);

  const int M = BB_ * HW_;  // 8192 tokens

  // 1) prep: weights->bf16 (x4 vec), t/xT transpose, zero sums
  prep_kernel<<<2336, 256, 0, stream>>>(x, pos, qkv_w, proj_w, pw_w, t_bf,
                                        xT_bf, wts, sums);
  // 2) qkv GEMM (BK=64, XCD-local bm, LDS-staged q/k + V stores)
  gemm_qkv<<<dim3(C3_ / 128, M / 128), 256, 0, stream>>>(
      t_bf, qkvw_bf, qkv_bf, vtb, qsum, ksum);
  // 3) flash attention (128q/block, K=32 PV via fragment concat) -> attn_out
  attn_mfma_kernel<<<BB_ * NH_ * (HW_ / 128), 256, 0, stream>>>(
      qkv_bf, vtb, qsum, ksum, temperature, t_bf);
  // 4) proj GEMM (BK=64, XCD-local bm, LDS-staged stores) -> proj_bf
  gemm_n64<1><<<dim3(C_ / 64, M / 128), 256, 0, stream>>>(
      t_bf, projw_bf, proj_b, proj_bf, nullptr, C_, C_);
  // 5) LayerNorm + residual(xT) -> y_bf (in place over xT), wave-per-token
  ln_residual_kernel<<<M / 4, 256, 0, stream>>>(proj_bf, xT_bf, ln_g, ln_b,
                                                xT_bf);
  // 6) depthwise 3x3 (sliding-window) on bf16 y -> dw_out (reuses t region)
  dwconv_kernel<<<M / 16, 256, 0, stream>>>(xT_bf, dw_w, dw_b, t_bf);
  // 7) pointwise GEMM (BK=64, XCD-local bm) + pw_b + residual, NCHW -> out
  gemm_n64<2><<<dim3(C_ / 64, M / 128), 256, 0, stream>>>(
      t_bf, pww_bf, pw_b, out, xT_bf, C_, C_);
}